// Round 6
// baseline (1549.018 us; speedup 1.0000x reference)
//
#include <hip/hip_runtime.h>
#include <math.h>

#define NN 100000
#define EE 800000
#define DH 128
#define NL 16
#define GEMM_GRID 1563
#define SG_GRID 391      // ceil(100000 / 256) for 16-wave spmm_gemm blocks
#define NSLOT 32

typedef __bf16 bf16x8 __attribute__((ext_vector_type(8)));
typedef float f32x4 __attribute__((ext_vector_type(4)));

// ---------------- CSR build ----------------
__global__ void k_hist(const int* __restrict__ row, int* __restrict__ cnt) {
    int e = blockIdx.x * 256 + threadIdx.x;
    if (e < EE) atomicAdd(&cnt[row[e]], 1);
}

__global__ void k_scan1(const int* __restrict__ cnt, int* __restrict__ rp, int* __restrict__ part) {
    __shared__ int buf[512];
    int tid = threadIdx.x;
    int i = blockIdx.x * 512 + tid;
    int v = (i < NN) ? cnt[i] : 0;
    buf[tid] = v;
    __syncthreads();
    for (int off = 1; off < 512; off <<= 1) {
        int x = (tid >= off) ? buf[tid - off] : 0;
        __syncthreads();
        buf[tid] += x;
        __syncthreads();
    }
    if (i < NN) rp[i] = buf[tid] - v;
    if (tid == 511) part[blockIdx.x] = buf[511];
}

__global__ void k_scan2(int* __restrict__ part, int nparts) {
    __shared__ int buf[256];
    int tid = threadIdx.x;
    int v = (tid < nparts) ? part[tid] : 0;
    buf[tid] = v;
    __syncthreads();
    for (int off = 1; off < 256; off <<= 1) {
        int x = (tid >= off) ? buf[tid - off] : 0;
        __syncthreads();
        buf[tid] += x;
        __syncthreads();
    }
    if (tid < nparts) part[tid] = buf[tid] - v;
}

__global__ void k_scan3(int* __restrict__ rp, const int* __restrict__ part) {
    int i = blockIdx.x * 512 + threadIdx.x;
    if (i < NN) rp[i] += part[blockIdx.x];
    if (i == 0) rp[NN] = EE;
}

// w prescaled by (1-ALPHA)=0.9 so the gather loop is a pure fma chain
__global__ void k_fill(const int* __restrict__ row, const int* __restrict__ col,
                       const float* __restrict__ w, const int* __restrict__ rp,
                       int* __restrict__ fil, int2* __restrict__ ep) {
    int e = blockIdx.x * 256 + threadIdx.x;
    if (e >= EE) return;
    int r = row[e];
    int pos = rp[r] + atomicAdd(&fil[r], 1);
    ep[pos] = make_int2(col[e], __float_as_int(0.9f * w[e]));
}

// ---------------- weight prep: split hi/lo bf16 + swizzle to MFMA fragment order ----------------
// frag[t][ks][lane][e] = M[k][j], j = t*16 + (lane&15), k = ks*32 + (lane>>4)*8 + e
__global__ void k_prep_w(const float* __restrict__ convW, const float* __restrict__ Win,
                         __bf16* __restrict__ Bhi, __bf16* __restrict__ Blo) {
    int l = blockIdx.x;
    const float* W;
    float beta, ob;
    if (l < NL) {
        beta = logf(0.5f / (float)(l + 1) + 1.0f);
        ob = 1.0f - beta;
        W = convW + (size_t)l * DH * DH;
    } else {
        beta = 1.0f;
        ob = 0.0f;
        W = Win;
    }
    __bf16* bh = Bhi + (size_t)l * DH * DH;
    __bf16* bl = Blo + (size_t)l * DH * DH;
    for (int i = threadIdx.x; i < DH * DH; i += 256) {
        int k = i >> 7, j = i & 127;
        float v = beta * W[i] + ((k == j) ? ob : 0.f);
        __bf16 hv = (__bf16)v;
        int t = j >> 4, n = j & 15, ks = k >> 5, quad = (k >> 3) & 3, e = k & 7;
        int off = ((t * 4 + ks) * 64 + quad * 16 + n) * 8 + e;
        bh[off] = hv;
        bl[off] = (__bf16)(v - (float)hv);
    }
}

__global__ void k_prep_out(const float* __restrict__ Wout, __bf16* __restrict__ Bhi, __bf16* __restrict__ Blo) {
    for (int i = threadIdx.x; i < DH * 48; i += 256) {
        int k = i / 48, j = i % 48;
        float v = (j < 40) ? Wout[k * 40 + j] : 0.f;
        __bf16 hv = (__bf16)v;
        int t = j >> 4, n = j & 15, ks = k >> 5, quad = (k >> 3) & 3, e = k & 7;
        int off = ((t * 4 + ks) * 64 + quad * 16 + n) * 8 + e;
        Bhi[off] = hv;
        Blo[off] = (__bf16)(v - (float)hv);
    }
}

__device__ inline void split8(const float* p, bf16x8& hi, bf16x8& lo) {
    f32x4 v0 = *(const f32x4*)p;
    f32x4 v1 = *(const f32x4*)(p + 4);
#pragma unroll
    for (int j = 0; j < 4; ++j) {
        __bf16 h0 = (__bf16)v0[j];
        hi[j] = h0;
        lo[j] = (__bf16)(v0[j] - (float)h0);
        __bf16 h1 = (__bf16)v1[j];
        hi[4 + j] = h1;
        lo[4 + j] = (__bf16)(v1[j] - (float)h1);
    }
}

#define MFMA(a, b, c) __builtin_amdgcn_mfma_f32_16x16x32_bf16(a, b, c, 0, 0, 0)

// ---------------- int8 group quantization (32-feature groups, pow2 scale) ----------------
// group scale s = 2^(eb-127), eb stored as one byte; value byte u: v ~ (u-128)*s.
// eb chosen so |v|max/s in [64,128) -> quant error <= s/2 <= 0.78% of group max.
__device__ inline float dec_scale(unsigned int sc4, int ks) {
    return __uint_as_float(((sc4 >> (8 * ks)) & 0xffu) << 23);
}

// x0 bf16 -> int8 groups (one thread per 32-feature group)
__global__ void k_cvt8(const __bf16* __restrict__ src, unsigned char* __restrict__ q8,
                       unsigned char* __restrict__ sc) {
    int t = blockIdx.x * 256 + threadIdx.x;
    if (t >= NN * 4) return;
    const __bf16* p = src + (size_t)t * 32;
    float v[32];
    float mx = 0.f;
#pragma unroll
    for (int i = 0; i < 4; ++i) {
        bf16x8 b = *(const bf16x8*)(p + i * 8);
#pragma unroll
        for (int c = 0; c < 8; ++c) {
            float f = (float)b[c];
            v[i * 8 + c] = f;
            mx = fmaxf(mx, fabsf(f));
        }
    }
    unsigned int em = (__float_as_uint(mx) >> 23) & 0xffu;
    unsigned int eb;
    float sinv;
    if (em < 7) { eb = 0; sinv = 0.f; }
    else { eb = em - 6; sinv = __uint_as_float((254 - eb) << 23); }
    sc[t] = (unsigned char)eb;
    unsigned int ww[8];
#pragma unroll
    for (int k = 0; k < 8; ++k) {
        unsigned int u = 0;
#pragma unroll
        for (int c = 0; c < 4; ++c) {
            unsigned int q = (unsigned int)rintf(fminf(fmaf(v[k * 4 + c], sinv, 128.f), 255.f));
            u |= q << (8 * c);
        }
        ww[k] = u;
    }
    uint4* dst = (uint4*)&q8[(size_t)t * 32];
    dst[0] = make_uint4(ww[0], ww[1], ww[2], ww[3]);
    dst[1] = make_uint4(ww[4], ww[5], ww[6], ww[7]);
}

// ---------------- FUSED SpMM + mix + layer GEMM (int8 gather operand) ----------------
// R4 structure (16 waves, 64KB LDS B-tile, 2 blocks/CU). Gather reads int8 rows
// (128B + 4B scales) instead of bf16 (256B): the gather is at a structural
// ~2.2 TB/s L2-miss-path ceiling (R4: occupancy 26->47% changed nothing), so
// traffic reduction is the only lever. decode: (ubyte - 128) * 2^(eb-127).
__global__ __launch_bounds__(1024, 8) void k_spmm_gemm(const unsigned char* __restrict__ hin8,
                                                       const unsigned char* __restrict__ hinsc,
                                                       const unsigned char* __restrict__ x08,
                                                       const unsigned char* __restrict__ x0sc,
                                                       const int* __restrict__ rp, const int2* __restrict__ ep,
                                                       __bf16* __restrict__ aout,
                                                       const __bf16* __restrict__ Bhi, const __bf16* __restrict__ Blo,
                                                       float* __restrict__ stats32) {
    __shared__ __bf16 Bs[2 * DH * DH];  // [hi|lo] in MFMA fragment order
    __shared__ float red[2][16][DH];
    int tid = threadIdx.x;
    {
        const f32x4* sh = (const f32x4*)Bhi;
        const f32x4* sl = (const f32x4*)Blo;
        f32x4* dh = (f32x4*)Bs;
        f32x4* dl = (f32x4*)(Bs + DH * DH);
#pragma unroll
        for (int i = 0; i < 2; ++i) {
            dh[tid + i * 1024] = sh[tid + i * 1024];
            dl[tid + i * 1024] = sl[tid + i * 1024];
        }
    }
    // no sync yet: gather phase doesn't touch Bs; sync sits right before MFMA.

    int wave = tid >> 6, lane = tid & 63;
    int n = lane & 15, quad = lane >> 4;
    int r0 = blockIdx.x * 256 + wave * 16;
    int node = r0 + n;
    int nc = (node < NN) ? node : (NN - 1);

    // spmm acc = 0.1*x0 + 0.9*Adj@h, feats quad*8 + ks*32 + c
    float acc[4][8];
    {
        unsigned int s4 = *(const unsigned int*)&x0sc[(size_t)nc * 4];
        const unsigned char* px = x08 + (size_t)nc * DH + quad * 8;
#pragma unroll
        for (int ks = 0; ks < 4; ++ks) {
            float ws0 = 0.1f * dec_scale(s4, ks);
            uint2 u = *(const uint2*)(px + ks * 32);
#pragma unroll
            for (int c = 0; c < 4; ++c) {
                acc[ks][c] = ws0 * ((float)((u.x >> (8 * c)) & 0xffu) - 128.f);
                acc[ks][4 + c] = ws0 * ((float)((u.y >> (8 * c)) & 0xffu) - 128.f);
            }
        }
    }
    int s = 0, e = 0;
    if (node < NN) { s = rp[node]; e = rp[node + 1]; }  // rp OOB guard for padded rows
    const unsigned char* hq = hin8 + quad * 8;
    int j = s;
    for (; j + 1 < e; j += 2) {
        int2 p0 = ep[j], p1 = ep[j + 1];
        float w0 = __int_as_float(p0.y), w1 = __int_as_float(p1.y);
        unsigned int s40 = *(const unsigned int*)&hinsc[(size_t)p0.x * 4];
        unsigned int s41 = *(const unsigned int*)&hinsc[(size_t)p1.x * 4];
        const unsigned char* q0 = hq + (size_t)p0.x * DH;
        const unsigned char* q1 = hq + (size_t)p1.x * DH;
#pragma unroll
        for (int ks = 0; ks < 4; ++ks) {
            float ws0 = w0 * dec_scale(s40, ks);
            float ws1 = w1 * dec_scale(s41, ks);
            uint2 u0 = *(const uint2*)(q0 + ks * 32);
            uint2 u1 = *(const uint2*)(q1 + ks * 32);
#pragma unroll
            for (int c = 0; c < 4; ++c) {
                acc[ks][c] = fmaf(ws0, (float)((u0.x >> (8 * c)) & 0xffu) - 128.f, acc[ks][c]);
                acc[ks][4 + c] = fmaf(ws0, (float)((u0.y >> (8 * c)) & 0xffu) - 128.f, acc[ks][4 + c]);
                acc[ks][c] = fmaf(ws1, (float)((u1.x >> (8 * c)) & 0xffu) - 128.f, acc[ks][c]);
                acc[ks][4 + c] = fmaf(ws1, (float)((u1.y >> (8 * c)) & 0xffu) - 128.f, acc[ks][4 + c]);
            }
        }
    }
    if (j < e) {
        int2 pe = ep[j];
        float w = __int_as_float(pe.y);
        unsigned int s4 = *(const unsigned int*)&hinsc[(size_t)pe.x * 4];
        const unsigned char* qp = hq + (size_t)pe.x * DH;
#pragma unroll
        for (int ks = 0; ks < 4; ++ks) {
            float ws = w * dec_scale(s4, ks);
            uint2 u = *(const uint2*)(qp + ks * 32);
#pragma unroll
            for (int c = 0; c < 4; ++c) {
                acc[ks][c] = fmaf(ws, (float)((u.x >> (8 * c)) & 0xffu) - 128.f, acc[ks][c]);
                acc[ks][4 + c] = fmaf(ws, (float)((u.y >> (8 * c)) & 0xffu) - 128.f, acc[ks][4 + c]);
            }
        }
    }

    // in-register A fragments
    bf16x8 av[4];
#pragma unroll
    for (int ks = 0; ks < 4; ++ks)
#pragma unroll
        for (int c = 0; c < 8; ++c) av[ks][c] = (__bf16)acc[ks][c];

    __syncthreads();  // Bs staging complete across all waves

    f32x4 gacc[8];
#pragma unroll
    for (int t = 0; t < 8; ++t) gacc[t] = (f32x4){0.f, 0.f, 0.f, 0.f};

#pragma unroll
    for (int ks = 0; ks < 4; ++ks) {
#pragma unroll
        for (int t = 0; t < 8; ++t) {
            int base = ((t * 4 + ks) * 64 + lane) * 8;
            bf16x8 bh = *(const bf16x8*)&Bs[base];
            bf16x8 bl = *(const bf16x8*)&Bs[DH * DH + base];
            gacc[t] = MFMA(av[ks], bh, gacc[t]);
            gacc[t] = MFMA(av[ks], bl, gacc[t]);
        }
    }

#pragma unroll
    for (int t = 0; t < 8; ++t) {
        float sm = 0.f, qq = 0.f;
#pragma unroll
        for (int r = 0; r < 4; ++r) {
            int row = r0 + quad * 4 + r;
            float v = gacc[t][r];
            if (row < NN) {
                aout[(size_t)row * DH + t * 16 + n] = (__bf16)v;
                sm += v;
                qq += v * v;
            }
        }
        sm += __shfl_xor(sm, 16); sm += __shfl_xor(sm, 32);
        qq += __shfl_xor(qq, 16); qq += __shfl_xor(qq, 32);
        if (quad == 0) {
            red[0][wave][t * 16 + n] = sm;
            red[1][wave][t * 16 + n] = qq;
        }
    }
    __syncthreads();
    if (tid < 256) {
        int which = tid >> 7, jj = tid & 127;
        float tot = 0.f;
#pragma unroll
        for (int w = 0; w < 16; ++w) tot += red[which][w][jj];
        atomicAdd(&stats32[(size_t)(blockIdx.x & (NSLOT - 1)) * 256 + tid], tot);
    }
}

// ---------------- input GEMM: x0 = relu(X @ Win + bin), fp32 A split on the fly, B in LDS ----------------
__global__ __launch_bounds__(256) void k_lin_in(const float* __restrict__ X,
                                                const __bf16* __restrict__ Bhi, const __bf16* __restrict__ Blo,
                                                const float* __restrict__ bin, __bf16* __restrict__ x0) {
    __shared__ __bf16 Bs[2 * DH * DH];
    int tid = threadIdx.x;
    {
        const f32x4* sh = (const f32x4*)Bhi;
        const f32x4* sl = (const f32x4*)Blo;
        f32x4* dh = (f32x4*)Bs;
        f32x4* dl = (f32x4*)(Bs + DH * DH);
#pragma unroll
        for (int i = 0; i < 8; ++i) {
            dh[tid + i * 256] = sh[tid + i * 256];
            dl[tid + i * 256] = sl[tid + i * 256];
        }
    }
    __syncthreads();

    int wave = tid >> 6, lane = tid & 63;
    int n = lane & 15, quad = lane >> 4;
    int r0 = blockIdx.x * 64 + wave * 16;
    int arow = r0 + n;
    if (arow > NN - 1) arow = NN - 1;
    const float* pa = X + (size_t)arow * DH + quad * 8;

    f32x4 acc[8];
#pragma unroll
    for (int t = 0; t < 8; ++t) acc[t] = (f32x4){0.f, 0.f, 0.f, 0.f};

#pragma unroll
    for (int ks = 0; ks < 4; ++ks) {
        bf16x8 ah, al;
        split8(pa + ks * 32, ah, al);
#pragma unroll
        for (int t = 0; t < 8; ++t) {
            int base = ((t * 4 + ks) * 64 + lane) * 8;
            bf16x8 bh = *(const bf16x8*)&Bs[base];
            bf16x8 bl = *(const bf16x8*)&Bs[DH * DH + base];
            acc[t] = MFMA(ah, bh, acc[t]);
            acc[t] = MFMA(al, bh, acc[t]);
            acc[t] = MFMA(ah, bl, acc[t]);
        }
    }

#pragma unroll
    for (int t = 0; t < 8; ++t) {
        float bj = bin[t * 16 + n];
#pragma unroll
        for (int r = 0; r < 4; ++r) {
            int row = r0 + quad * 4 + r;
            if (row < NN) {
                float v = fmaxf(acc[t][r] + bj, 0.f);
                x0[(size_t)row * DH + t * 16 + n] = (__bf16)v;
            }
        }
    }
}

// ---------------- output GEMM: out = h @ Wout + bout (3 tiles of 16 cols), B in LDS ----------------
__global__ __launch_bounds__(256) void k_gemm_out(const __bf16* __restrict__ A,
                                                  const __bf16* __restrict__ Bhi, const __bf16* __restrict__ Blo,
                                                  const float* __restrict__ bout, float* __restrict__ out) {
    __shared__ __bf16 Bs[2 * 48 * DH];
    int tid = threadIdx.x;
    {
        const f32x4* sh = (const f32x4*)Bhi;
        const f32x4* sl = (const f32x4*)Blo;
        f32x4* dh = (f32x4*)Bs;
        f32x4* dl = (f32x4*)(Bs + 48 * DH);
#pragma unroll
        for (int i = 0; i < 3; ++i) {
            dh[tid + i * 256] = sh[tid + i * 256];
            dl[tid + i * 256] = sl[tid + i * 256];
        }
    }
    __syncthreads();

    int wave = tid >> 6, lane = tid & 63;
    int n = lane & 15, quad = lane >> 4;
    int r0 = blockIdx.x * 64 + wave * 16;
    int arow = r0 + n;
    if (arow > NN - 1) arow = NN - 1;
    const __bf16* pa = A + (size_t)arow * DH + quad * 8;

    f32x4 acc[3];
#pragma unroll
    for (int t = 0; t < 3; ++t) acc[t] = (f32x4){0.f, 0.f, 0.f, 0.f};

#pragma unroll
    for (int ks = 0; ks < 4; ++ks) {
        bf16x8 av = *(const bf16x8*)(pa + ks * 32);
#pragma unroll
        for (int t = 0; t < 3; ++t) {
            int base = ((t * 4 + ks) * 64 + lane) * 8;
            bf16x8 bh = *(const bf16x8*)&Bs[base];
            bf16x8 bl = *(const bf16x8*)&Bs[48 * DH + base];
            acc[t] = MFMA(av, bh, acc[t]);
            acc[t] = MFMA(av, bl, acc[t]);
        }
    }

#pragma unroll
    for (int t = 0; t < 3; ++t) {
        int j = t * 16 + n;
        float bj = (j < 40) ? bout[j] : 0.f;
#pragma unroll
        for (int r = 0; r < 4; ++r) {
            int row = r0 + quad * 4 + r;
            if (row < NN && j < 40) out[(size_t)row * 40 + j] = acc[t][r] + bj;
        }
    }
}

// ---------------- fused slot-reduce + BN-finalize + update + int8 re-encode ----------------
// h_out = relu(a*sc + sh + h_in); also emits h8 (int8 groups) + hsc for the next
// layer's gather. 4 consecutive lanes share a 32-col group -> shfl_xor(1,2) max.
__global__ __launch_bounds__(256) void k_update(const __bf16* __restrict__ a, const __bf16* __restrict__ hin,
                                                __bf16* __restrict__ hout,
                                                unsigned char* __restrict__ h8, unsigned char* __restrict__ hsc,
                                                const float* __restrict__ stats32,
                                                const float* __restrict__ gamma, const float* __restrict__ bbeta) {
    __shared__ float scb[DH], shb[DH];
    int tid = threadIdx.x;
    if (tid < DH) {
        float s = 0.f, q = 0.f;
#pragma unroll
        for (int sl = 0; sl < NSLOT; ++sl) {
            s += stats32[(size_t)sl * 256 + tid];
            q += stats32[(size_t)sl * 256 + 128 + tid];
        }
        float mu = s * (1.0f / NN);
        float var = q * (1.0f / NN) - mu * mu;
        if (var < 0.f) var = 0.f;
        float sc = gamma[tid] * rsqrtf(var + 1e-5f);
        scb[tid] = sc;
        shb[tid] = bbeta[tid] - mu * sc;
    }
    __syncthreads();

    int idx = blockIdx.x * 256 + tid;
    int j0 = (idx & 15) * 8;
    bf16x8 av = ((const bf16x8*)a)[idx];
    bf16x8 hv = ((const bf16x8*)hin)[idx];
    bf16x8 o;
    float vv[8];
    float mx = 0.f;
#pragma unroll
    for (int c = 0; c < 8; ++c) {
        int j = j0 + c;
        float v = fmaxf(fmaf((float)av[c], scb[j], shb[j]) + (float)hv[c], 0.f);
        vv[c] = v;
        mx = fmaxf(mx, v);          // relu'd: v >= 0
        o[c] = (__bf16)v;
    }
    ((bf16x8*)hout)[idx] = o;

    // group max across the 4 lanes sharing cols [g*32, g*32+32)
    mx = fmaxf(mx, __shfl_xor(mx, 1));
    mx = fmaxf(mx, __shfl_xor(mx, 2));
    unsigned int em = (__float_as_uint(mx) >> 23) & 0xffu;
    unsigned int eb;
    float sinv;
    if (em < 7) { eb = 0; sinv = 0.f; }
    else { eb = em - 6; sinv = __uint_as_float((254 - eb) << 23); }
    if ((tid & 3) == 0) hsc[(size_t)(idx >> 4) * 4 + ((idx >> 2) & 3)] = (unsigned char)eb;
    uint2 pk;
    pk.x = 0; pk.y = 0;
#pragma unroll
    for (int c = 0; c < 4; ++c) {
        unsigned int q0 = (unsigned int)rintf(fminf(fmaf(vv[c], sinv, 128.f), 255.f));
        unsigned int q1 = (unsigned int)rintf(fminf(fmaf(vv[4 + c], sinv, 128.f), 255.f));
        pk.x |= q0 << (8 * c);
        pk.y |= q1 << (8 * c);
    }
    *(uint2*)&h8[(size_t)idx * 8] = pk;
}

extern "C" void kernel_launch(void* const* d_in, const int* in_sizes, int n_in,
                              void* d_out, int out_size, void* d_ws, size_t ws_size,
                              hipStream_t stream) {
    const float* x = (const float*)d_in[0];
    const float* ew = (const float*)d_in[1];
    const float* Win = (const float*)d_in[2];
    const float* bin = (const float*)d_in[3];
    const float* convW = (const float*)d_in[4];
    const float* gamma = (const float*)d_in[5];
    const float* bbeta = (const float*)d_in[6];
    const float* Wout = (const float*)d_in[7];
    const float* bout = (const float*)d_in[8];
    const int* erow = (const int*)d_in[9];
    const int* ecol = (const int*)d_in[10];
    float* out = (float*)d_out;

    char* wsp = (char*)d_ws;
    size_t off = 0;
    auto alloc = [&](size_t bytes) -> void* {
        void* p = wsp + off;
        off += (bytes + 255) & ~(size_t)255;
        return p;
    };
    __bf16* x0 = (__bf16*)alloc((size_t)NN * DH * 2);
    __bf16* h = (__bf16*)alloc((size_t)NN * DH * 2);
    __bf16* a = (__bf16*)alloc((size_t)NN * DH * 2);
    unsigned char* x08 = (unsigned char*)alloc((size_t)NN * DH);
    unsigned char* h8 = (unsigned char*)alloc((size_t)NN * DH);
    unsigned char* x0sc = (unsigned char*)alloc((size_t)NN * 4);
    unsigned char* hsc = (unsigned char*)alloc((size_t)NN * 4);
    int* rp = (int*)alloc((NN + 1) * 4);
    // zero-init region: cnt | fil | stats32 as ONE memset
    size_t zero_bytes = (size_t)NN * 4 + (size_t)NN * 4 + (size_t)NL * NSLOT * 256 * 4;
    int* cnt = (int*)alloc(zero_bytes);
    int* fil = cnt + NN;
    float* stats32 = (float*)(fil + NN);
    int2* ep = (int2*)alloc((size_t)EE * 8);
    int* part = (int*)alloc(256 * 4);
    __bf16* Bhi = (__bf16*)alloc((size_t)(NL + 1) * DH * DH * 2);
    __bf16* Blo = (__bf16*)alloc((size_t)(NL + 1) * DH * DH * 2);
    __bf16* Bohi = (__bf16*)alloc((size_t)DH * 48 * 2);
    __bf16* Bolo = (__bf16*)alloc((size_t)DH * 48 * 2);

    hipMemsetAsync(cnt, 0, zero_bytes, stream);

    k_hist<<<3125, 256, 0, stream>>>(erow, cnt);
    k_scan1<<<196, 512, 0, stream>>>(cnt, rp, part);
    k_scan2<<<1, 256, 0, stream>>>(part, 196);
    k_scan3<<<196, 512, 0, stream>>>(rp, part);
    k_fill<<<3125, 256, 0, stream>>>(erow, ecol, ew, rp, fil, ep);

    k_prep_w<<<NL + 1, 256, 0, stream>>>(convW, Win, Bhi, Blo);
    k_prep_out<<<1, 256, 0, stream>>>(Wout, Bohi, Bolo);

    k_lin_in<<<GEMM_GRID, 256, 0, stream>>>(x, Bhi + (size_t)NL * DH * DH, Blo + (size_t)NL * DH * DH, bin, x0);
    k_cvt8<<<1563, 256, 0, stream>>>(x0, x08, x0sc);

    for (int l = 0; l < NL; ++l) {
        const unsigned char* hin8 = (l == 0) ? x08 : h8;
        const unsigned char* hinsc = (l == 0) ? x0sc : hsc;
        const __bf16* hin = (l == 0) ? x0 : h;
        float* st = stats32 + (size_t)l * NSLOT * 256;
        k_spmm_gemm<<<SG_GRID, 1024, 0, stream>>>(hin8, hinsc, x08, x0sc, rp, ep, a,
                                                  Bhi + (size_t)l * DH * DH, Blo + (size_t)l * DH * DH, st);
        k_update<<<6250, 256, 0, stream>>>(a, hin, h, h8, hsc, st, gamma + l * DH, bbeta + l * DH);
    }
    k_gemm_out<<<GEMM_GRID, 256, 0, stream>>>(h, Bohi, Bolo, bout, out);
}

// Round 7
// 1258.625 us; speedup vs baseline: 1.2307x; 1.2307x over previous
//
#include <hip/hip_runtime.h>
#include <math.h>

#define NN 100000
#define EE 800000
#define DH 128
#define NL 16
#define GEMM_GRID 1563
#define SG_GRID 782      // ceil(100000 / 128) for 8-wave spmm_gemm blocks
#define NSLOT 32

typedef __bf16 bf16x8 __attribute__((ext_vector_type(8)));
typedef float f32x4 __attribute__((ext_vector_type(4)));

// ---------------- CSR build ----------------
__global__ void k_hist(const int* __restrict__ row, int* __restrict__ cnt) {
    int e = blockIdx.x * 256 + threadIdx.x;
    if (e < EE) atomicAdd(&cnt[row[e]], 1);
}

__global__ void k_scan1(const int* __restrict__ cnt, int* __restrict__ rp, int* __restrict__ part) {
    __shared__ int buf[512];
    int tid = threadIdx.x;
    int i = blockIdx.x * 512 + tid;
    int v = (i < NN) ? cnt[i] : 0;
    buf[tid] = v;
    __syncthreads();
    for (int off = 1; off < 512; off <<= 1) {
        int x = (tid >= off) ? buf[tid - off] : 0;
        __syncthreads();
        buf[tid] += x;
        __syncthreads();
    }
    if (i < NN) rp[i] = buf[tid] - v;
    if (tid == 511) part[blockIdx.x] = buf[511];
}

__global__ void k_scan2(int* __restrict__ part, int nparts) {
    __shared__ int buf[256];
    int tid = threadIdx.x;
    int v = (tid < nparts) ? part[tid] : 0;
    buf[tid] = v;
    __syncthreads();
    for (int off = 1; off < 256; off <<= 1) {
        int x = (tid >= off) ? buf[tid - off] : 0;
        __syncthreads();
        buf[tid] += x;
        __syncthreads();
    }
    if (tid < nparts) part[tid] = buf[tid] - v;
}

__global__ void k_scan3(int* __restrict__ rp, const int* __restrict__ part) {
    int i = blockIdx.x * 512 + threadIdx.x;
    if (i < NN) rp[i] += part[blockIdx.x];
    if (i == 0) rp[NN] = EE;
}

// w prescaled by (1-ALPHA)=0.9 so the gather loop is a pure fma chain
__global__ void k_fill(const int* __restrict__ row, const int* __restrict__ col,
                       const float* __restrict__ w, const int* __restrict__ rp,
                       int* __restrict__ fil, int2* __restrict__ ep) {
    int e = blockIdx.x * 256 + threadIdx.x;
    if (e >= EE) return;
    int r = row[e];
    int pos = rp[r] + atomicAdd(&fil[r], 1);
    ep[pos] = make_int2(col[e], __float_as_int(0.9f * w[e]));
}

// ---------------- weight prep: split hi/lo bf16 + swizzle to MFMA fragment order ----------------
// frag[t][ks][lane][e] = M[k][j], j = t*16 + (lane&15), k = ks*32 + (lane>>4)*8 + e
__global__ void k_prep_w(const float* __restrict__ convW, const float* __restrict__ Win,
                         __bf16* __restrict__ Bhi, __bf16* __restrict__ Blo) {
    int l = blockIdx.x;
    const float* W;
    float beta, ob;
    if (l < NL) {
        beta = logf(0.5f / (float)(l + 1) + 1.0f);
        ob = 1.0f - beta;
        W = convW + (size_t)l * DH * DH;
    } else {
        beta = 1.0f;
        ob = 0.0f;
        W = Win;
    }
    __bf16* bh = Bhi + (size_t)l * DH * DH;
    __bf16* bl = Blo + (size_t)l * DH * DH;
    for (int i = threadIdx.x; i < DH * DH; i += 256) {
        int k = i >> 7, j = i & 127;
        float v = beta * W[i] + ((k == j) ? ob : 0.f);
        __bf16 hv = (__bf16)v;
        int t = j >> 4, n = j & 15, ks = k >> 5, quad = (k >> 3) & 3, e = k & 7;
        int off = ((t * 4 + ks) * 64 + quad * 16 + n) * 8 + e;
        bh[off] = hv;
        bl[off] = (__bf16)(v - (float)hv);
    }
}

__global__ void k_prep_out(const float* __restrict__ Wout, __bf16* __restrict__ Bhi, __bf16* __restrict__ Blo) {
    for (int i = threadIdx.x; i < DH * 48; i += 256) {
        int k = i / 48, j = i % 48;
        float v = (j < 40) ? Wout[k * 40 + j] : 0.f;
        __bf16 hv = (__bf16)v;
        int t = j >> 4, n = j & 15, ks = k >> 5, quad = (k >> 3) & 3, e = k & 7;
        int off = ((t * 4 + ks) * 64 + quad * 16 + n) * 8 + e;
        Bhi[off] = hv;
        Blo[off] = (__bf16)(v - (float)hv);
    }
}

__device__ inline void split8(const float* p, bf16x8& hi, bf16x8& lo) {
    f32x4 v0 = *(const f32x4*)p;
    f32x4 v1 = *(const f32x4*)(p + 4);
#pragma unroll
    for (int j = 0; j < 4; ++j) {
        __bf16 h0 = (__bf16)v0[j];
        hi[j] = h0;
        lo[j] = (__bf16)(v0[j] - (float)h0);
        __bf16 h1 = (__bf16)v1[j];
        hi[4 + j] = h1;
        lo[4 + j] = (__bf16)(v1[j] - (float)h1);
    }
}

#define MFMA(a, b, c) __builtin_amdgcn_mfma_f32_16x16x32_bf16(a, b, c, 0, 0, 0)

// ---------------- int8 group quantization (32-feature groups, pow2 scale) ----------------
// group scale s = 2^(eb-127); value byte u: v ~ (u-128)*s.
// FRAGMENT-CONTIGUOUS layout: feature j (ks=j>>5, q=(j>>3)&3, c=j&7) stored at
// byte P(j) = (ks>>1)*64 + q*16 + (ks&1)*8 + c. Gather lane (n,q) then reads its
// 32 feats as TWO contiguous uint4 loads (offsets q*16 and 64+q*16), and each
// load instruction's 4 quads land in ONE 64B line.
__device__ inline float dec_scale(unsigned int sc4, int ks) {
    return __uint_as_float(((sc4 >> (8 * ks)) & 0xffu) << 23);
}

// decode 4 bytes of dw (feats c..c+3 of one ks) with bias folded into sumws:
// acc += ws * u8 ; final correction subtracts 128*sumws.
#define DEC_DW(dw, wsv, a0, a1, a2, a3)                         \
    {                                                           \
        a0 = fmaf(wsv, (float)((dw)&0xffu), a0);                \
        a1 = fmaf(wsv, (float)(((dw) >> 8) & 0xffu), a1);       \
        a2 = fmaf(wsv, (float)(((dw) >> 16) & 0xffu), a2);      \
        a3 = fmaf(wsv, (float)((dw) >> 24), a3);                \
    }

#define EDGE_FMA(S4, W, RA, RB)                                       \
    {                                                                 \
        float _w = (W);                                               \
        float _w0 = _w * dec_scale(S4, 0);                            \
        float _w1 = _w * dec_scale(S4, 1);                            \
        float _w2 = _w * dec_scale(S4, 2);                            \
        float _w3 = _w * dec_scale(S4, 3);                            \
        sw0 += _w0; sw1 += _w1; sw2 += _w2; sw3 += _w3;               \
        DEC_DW((RA).x, _w0, acc[0][0], acc[0][1], acc[0][2], acc[0][3]); \
        DEC_DW((RA).y, _w0, acc[0][4], acc[0][5], acc[0][6], acc[0][7]); \
        DEC_DW((RA).z, _w1, acc[1][0], acc[1][1], acc[1][2], acc[1][3]); \
        DEC_DW((RA).w, _w1, acc[1][4], acc[1][5], acc[1][6], acc[1][7]); \
        DEC_DW((RB).x, _w2, acc[2][0], acc[2][1], acc[2][2], acc[2][3]); \
        DEC_DW((RB).y, _w2, acc[2][4], acc[2][5], acc[2][6], acc[2][7]); \
        DEC_DW((RB).z, _w3, acc[3][0], acc[3][1], acc[3][2], acc[3][3]); \
        DEC_DW((RB).w, _w3, acc[3][4], acc[3][5], acc[3][6], acc[3][7]); \
    }

// x0 bf16 -> int8 groups (one thread per 32-feature group), fragment-contiguous layout
__global__ void k_cvt8(const __bf16* __restrict__ src, unsigned char* __restrict__ q8,
                       unsigned char* __restrict__ sc) {
    int t = blockIdx.x * 256 + threadIdx.x;
    if (t >= NN * 4) return;
    int node = t >> 2, ks = t & 3;
    const __bf16* p = src + (size_t)node * DH + ks * 32;
    float v[32];
    float mx = 0.f;
#pragma unroll
    for (int i = 0; i < 4; ++i) {
        bf16x8 b = *(const bf16x8*)(p + i * 8);
#pragma unroll
        for (int c = 0; c < 8; ++c) {
            float f = (float)b[c];
            v[i * 8 + c] = f;
            mx = fmaxf(mx, fabsf(f));
        }
    }
    unsigned int em = (__float_as_uint(mx) >> 23) & 0xffu;
    unsigned int eb;
    float sinv;
    if (em < 7) { eb = 0; sinv = 0.f; }
    else { eb = em - 6; sinv = __uint_as_float((254 - eb) << 23); }
    sc[(size_t)node * 4 + ks] = (unsigned char)eb;
    unsigned char* bp = q8 + (size_t)node * 128 + (ks >> 1) * 64 + (ks & 1) * 8;
#pragma unroll
    for (int q = 0; q < 4; ++q) {
        uint2 w;
        w.x = 0; w.y = 0;
#pragma unroll
        for (int c = 0; c < 4; ++c) {
            unsigned int q0 = (unsigned int)rintf(fminf(fmaf(v[q * 8 + c], sinv, 128.f), 255.f));
            unsigned int q1 = (unsigned int)rintf(fminf(fmaf(v[q * 8 + 4 + c], sinv, 128.f), 255.f));
            w.x |= q0 << (8 * c);
            w.y |= q1 << (8 * c);
        }
        *(uint2*)(bp + q * 16) = w;
    }
}

// ---------------- FUSED SpMM + mix + layer GEMM (int8, software-pipelined gather) ----------------
// R6 showed time invariant to bytes (FETCH halved, dur flat) and R4 to occupancy:
// the gather was exposing ~1 full memory round-trip per loop iteration because the
// compiler cannot hoist loads across the divergent backedge (cannot prove ep[j+2]
// in-bounds). Fix: 3-stage manual pipeline with CLAMPED speculative prefetch
// (indices clamped to EE-2; ep entries are always valid node ids, so the loads are
// safe and garbage values are simply unused). Iteration k: fma pair k (loaded 1 it
// ago), issue rows for pair k+1 (ep arrived), issue ep for pair k+2.
__global__ __launch_bounds__(512, 4) void k_spmm_gemm(const unsigned char* __restrict__ hin8,
                                                      const unsigned char* __restrict__ hinsc,
                                                      const unsigned char* __restrict__ x08,
                                                      const unsigned char* __restrict__ x0sc,
                                                      const int* __restrict__ rp, const int2* __restrict__ ep,
                                                      __bf16* __restrict__ aout,
                                                      const __bf16* __restrict__ Bhi, const __bf16* __restrict__ Blo,
                                                      float* __restrict__ stats32) {
    __shared__ __bf16 Bs[2 * DH * DH];  // [hi|lo] in MFMA fragment order
    __shared__ float red[2][8][DH];
    int tid = threadIdx.x;
    {
        const f32x4* sh = (const f32x4*)Bhi;
        const f32x4* sl = (const f32x4*)Blo;
        f32x4* dh = (f32x4*)Bs;
        f32x4* dl = (f32x4*)(Bs + DH * DH);
#pragma unroll
        for (int i = 0; i < 4; ++i) {
            dh[tid + i * 512] = sh[tid + i * 512];
            dl[tid + i * 512] = sl[tid + i * 512];
        }
    }
    // no sync yet: gather phase doesn't touch Bs; sync sits right before MFMA.

    int wave = tid >> 6, lane = tid & 63;
    int n = lane & 15, quad = lane >> 4;
    int r0 = blockIdx.x * 128 + wave * 16;
    int node = r0 + n;
    int nc = (node < NN) ? node : (NN - 1);

    float acc[4][8];
#pragma unroll
    for (int ks = 0; ks < 4; ++ks)
#pragma unroll
        for (int c = 0; c < 8; ++c) acc[ks][c] = 0.f;
    float sw0 = 0.f, sw1 = 0.f, sw2 = 0.f, sw3 = 0.f;

    // x0 self-term loads (issued first; consumed after prologue issues -> MLP)
    unsigned xs4 = *(const unsigned*)&x0sc[(size_t)nc * 4];
    const unsigned char* xb = x08 + (size_t)nc * 128 + quad * 16;
    uint4 xa = *(const uint4*)xb;
    uint4 xc = *(const uint4*)(xb + 64);

    int s = 0, e = 0;
    if (node < NN) { s = rp[node]; e = rp[node + 1]; }
    int cnt = e - s;
    int npairs = cnt >> 1;

    const unsigned char* hb = hin8 + quad * 16;

    int2 cP0, cP1, fP0, fP1;
    unsigned cS0, cS1;
    uint4 cA0, cB0, cA1, cB1;
    if (npairs > 0) {
        cP0 = ep[s]; cP1 = ep[s + 1];
        cS0 = *(const unsigned*)&hinsc[(size_t)cP0.x * 4];
        cS1 = *(const unsigned*)&hinsc[(size_t)cP1.x * 4];
        const unsigned char* b0 = hb + (size_t)cP0.x * 128;
        const unsigned char* b1 = hb + (size_t)cP1.x * 128;
        cA0 = *(const uint4*)b0; cB0 = *(const uint4*)(b0 + 64);
        cA1 = *(const uint4*)b1; cB1 = *(const uint4*)(b1 + 64);
        int jf = s + 2; if (jf > EE - 2) jf = EE - 2;
        fP0 = ep[jf]; fP1 = ep[jf + 1];
    }

    EDGE_FMA(xs4, 0.1f, xa, xc);   // weight 0.1 on x0 (alpha mix)

    int j = s;
    for (int it = 0; it < npairs; ++it) {
        // stage 1: ep prefetch for pair it+2 (clamped speculative)
        int j2 = j + 4; if (j2 > EE - 2) j2 = EE - 2;
        int2 eN0 = ep[j2], eN1 = ep[j2 + 1];
        // stage 2: scales + rows for pair it+1 (fP arrived 1 iter ago)
        unsigned tS0 = *(const unsigned*)&hinsc[(size_t)fP0.x * 4];
        unsigned tS1 = *(const unsigned*)&hinsc[(size_t)fP1.x * 4];
        const unsigned char* b0 = hb + (size_t)fP0.x * 128;
        const unsigned char* b1 = hb + (size_t)fP1.x * 128;
        uint4 tA0 = *(const uint4*)b0, tB0 = *(const uint4*)(b0 + 64);
        uint4 tA1 = *(const uint4*)b1, tB1 = *(const uint4*)(b1 + 64);
        // stage 3: fma pair it (loaded 1 iter ago; 8 loads remain in flight)
        EDGE_FMA(cS0, __int_as_float(cP0.y), cA0, cB0);
        EDGE_FMA(cS1, __int_as_float(cP1.y), cA1, cB1);
        // shift pipeline registers
        cP0 = fP0; cP1 = fP1; fP0 = eN0; fP1 = eN1;
        cS0 = tS0; cS1 = tS1;
        cA0 = tA0; cB0 = tB0; cA1 = tA1; cB1 = tB1;
        j += 2;
    }
    if (cnt & 1) {
        int2 pe = ep[e - 1];
        unsigned s4 = *(const unsigned*)&hinsc[(size_t)pe.x * 4];
        const unsigned char* bp = hb + (size_t)pe.x * 128;
        uint4 ra = *(const uint4*)bp, rb = *(const uint4*)(bp + 64);
        EDGE_FMA(s4, __int_as_float(pe.y), ra, rb);
    }

    // bias correction (u8 -> u8-128) + bf16 A fragments
    bf16x8 av[4];
    {
        float sws[4] = {sw0, sw1, sw2, sw3};
#pragma unroll
        for (int ks = 0; ks < 4; ++ks)
#pragma unroll
            for (int c = 0; c < 8; ++c)
                av[ks][c] = (__bf16)(acc[ks][c] - 128.0f * sws[ks]);
    }

    __syncthreads();  // Bs staging complete across all waves

    f32x4 gacc[8];
#pragma unroll
    for (int t = 0; t < 8; ++t) gacc[t] = (f32x4){0.f, 0.f, 0.f, 0.f};

#pragma unroll
    for (int ks = 0; ks < 4; ++ks) {
#pragma unroll
        for (int t = 0; t < 8; ++t) {
            int base = ((t * 4 + ks) * 64 + lane) * 8;
            bf16x8 bh = *(const bf16x8*)&Bs[base];
            bf16x8 bl = *(const bf16x8*)&Bs[DH * DH + base];
            gacc[t] = MFMA(av[ks], bh, gacc[t]);
            gacc[t] = MFMA(av[ks], bl, gacc[t]);
        }
    }

#pragma unroll
    for (int t = 0; t < 8; ++t) {
        float sm = 0.f, qq = 0.f;
#pragma unroll
        for (int r = 0; r < 4; ++r) {
            int row = r0 + quad * 4 + r;
            float v = gacc[t][r];
            if (row < NN) {
                aout[(size_t)row * DH + t * 16 + n] = (__bf16)v;
                sm += v;
                qq += v * v;
            }
        }
        sm += __shfl_xor(sm, 16); sm += __shfl_xor(sm, 32);
        qq += __shfl_xor(qq, 16); qq += __shfl_xor(qq, 32);
        if (quad == 0) {
            red[0][wave][t * 16 + n] = sm;
            red[1][wave][t * 16 + n] = qq;
        }
    }
    __syncthreads();
    if (tid < 256) {
        int which = tid >> 7, jj = tid & 127;
        float tot = 0.f;
#pragma unroll
        for (int w = 0; w < 8; ++w) tot += red[which][w][jj];
        atomicAdd(&stats32[(size_t)(blockIdx.x & (NSLOT - 1)) * 256 + tid], tot);
    }
}

// ---------------- input GEMM: x0 = relu(X @ Win + bin), fp32 A split on the fly, B in LDS ----------------
__global__ __launch_bounds__(256) void k_lin_in(const float* __restrict__ X,
                                                const __bf16* __restrict__ Bhi, const __bf16* __restrict__ Blo,
                                                const float* __restrict__ bin, __bf16* __restrict__ x0) {
    __shared__ __bf16 Bs[2 * DH * DH];
    int tid = threadIdx.x;
    {
        const f32x4* sh = (const f32x4*)Bhi;
        const f32x4* sl = (const f32x4*)Blo;
        f32x4* dh = (f32x4*)Bs;
        f32x4* dl = (f32x4*)(Bs + DH * DH);
#pragma unroll
        for (int i = 0; i < 8; ++i) {
            dh[tid + i * 256] = sh[tid + i * 256];
            dl[tid + i * 256] = sl[tid + i * 256];
        }
    }
    __syncthreads();

    int wave = tid >> 6, lane = tid & 63;
    int n = lane & 15, quad = lane >> 4;
    int r0 = blockIdx.x * 64 + wave * 16;
    int arow = r0 + n;
    if (arow > NN - 1) arow = NN - 1;
    const float* pa = X + (size_t)arow * DH + quad * 8;

    f32x4 acc[8];
#pragma unroll
    for (int t = 0; t < 8; ++t) acc[t] = (f32x4){0.f, 0.f, 0.f, 0.f};

#pragma unroll
    for (int ks = 0; ks < 4; ++ks) {
        bf16x8 ah, al;
        split8(pa + ks * 32, ah, al);
#pragma unroll
        for (int t = 0; t < 8; ++t) {
            int base = ((t * 4 + ks) * 64 + lane) * 8;
            bf16x8 bh = *(const bf16x8*)&Bs[base];
            bf16x8 bl = *(const bf16x8*)&Bs[DH * DH + base];
            acc[t] = MFMA(ah, bh, acc[t]);
            acc[t] = MFMA(al, bh, acc[t]);
            acc[t] = MFMA(ah, bl, acc[t]);
        }
    }

#pragma unroll
    for (int t = 0; t < 8; ++t) {
        float bj = bin[t * 16 + n];
#pragma unroll
        for (int r = 0; r < 4; ++r) {
            int row = r0 + quad * 4 + r;
            if (row < NN) {
                float v = fmaxf(acc[t][r] + bj, 0.f);
                x0[(size_t)row * DH + t * 16 + n] = (__bf16)v;
            }
        }
    }
}

// ---------------- output GEMM: out = h @ Wout + bout (3 tiles of 16 cols), B in LDS ----------------
__global__ __launch_bounds__(256) void k_gemm_out(const __bf16* __restrict__ A,
                                                  const __bf16* __restrict__ Bhi, const __bf16* __restrict__ Blo,
                                                  const float* __restrict__ bout, float* __restrict__ out) {
    __shared__ __bf16 Bs[2 * 48 * DH];
    int tid = threadIdx.x;
    {
        const f32x4* sh = (const f32x4*)Bhi;
        const f32x4* sl = (const f32x4*)Blo;
        f32x4* dh = (f32x4*)Bs;
        f32x4* dl = (f32x4*)(Bs + 48 * DH);
#pragma unroll
        for (int i = 0; i < 3; ++i) {
            dh[tid + i * 256] = sh[tid + i * 256];
            dl[tid + i * 256] = sl[tid + i * 256];
        }
    }
    __syncthreads();

    int wave = tid >> 6, lane = tid & 63;
    int n = lane & 15, quad = lane >> 4;
    int r0 = blockIdx.x * 64 + wave * 16;
    int arow = r0 + n;
    if (arow > NN - 1) arow = NN - 1;
    const __bf16* pa = A + (size_t)arow * DH + quad * 8;

    f32x4 acc[3];
#pragma unroll
    for (int t = 0; t < 3; ++t) acc[t] = (f32x4){0.f, 0.f, 0.f, 0.f};

#pragma unroll
    for (int ks = 0; ks < 4; ++ks) {
        bf16x8 av = *(const bf16x8*)(pa + ks * 32);
#pragma unroll
        for (int t = 0; t < 3; ++t) {
            int base = ((t * 4 + ks) * 64 + lane) * 8;
            bf16x8 bh = *(const bf16x8*)&Bs[base];
            bf16x8 bl = *(const bf16x8*)&Bs[48 * DH + base];
            acc[t] = MFMA(av, bh, acc[t]);
            acc[t] = MFMA(av, bl, acc[t]);
        }
    }

#pragma unroll
    for (int t = 0; t < 3; ++t) {
        int j = t * 16 + n;
        float bj = (j < 40) ? bout[j] : 0.f;
#pragma unroll
        for (int r = 0; r < 4; ++r) {
            int row = r0 + quad * 4 + r;
            if (row < NN && j < 40) out[(size_t)row * 40 + j] = acc[t][r] + bj;
        }
    }
}

// ---------------- fused slot-reduce + BN-finalize + update + int8 re-encode ----------------
// h_out = relu(a*sc + sh + h_in); also emits h8 (fragment-contiguous int8) + hsc.
// 4 consecutive threads share a 32-col group -> shfl_xor(1,2) max.
__global__ __launch_bounds__(256) void k_update(const __bf16* __restrict__ a, const __bf16* __restrict__ hin,
                                                __bf16* __restrict__ hout,
                                                unsigned char* __restrict__ h8, unsigned char* __restrict__ hsc,
                                                const float* __restrict__ stats32,
                                                const float* __restrict__ gamma, const float* __restrict__ bbeta) {
    __shared__ float scb[DH], shb[DH];
    int tid = threadIdx.x;
    if (tid < DH) {
        float s = 0.f, q = 0.f;
#pragma unroll
        for (int sl = 0; sl < NSLOT; ++sl) {
            s += stats32[(size_t)sl * 256 + tid];
            q += stats32[(size_t)sl * 256 + 128 + tid];
        }
        float mu = s * (1.0f / NN);
        float var = q * (1.0f / NN) - mu * mu;
        if (var < 0.f) var = 0.f;
        float sc = gamma[tid] * rsqrtf(var + 1e-5f);
        scb[tid] = sc;
        shb[tid] = bbeta[tid] - mu * sc;
    }
    __syncthreads();

    int idx = blockIdx.x * 256 + tid;
    int sub = idx & 15;
    int j0 = sub * 8;
    bf16x8 av = ((const bf16x8*)a)[idx];
    bf16x8 hv = ((const bf16x8*)hin)[idx];
    bf16x8 o;
    float vv[8];
    float mx = 0.f;
#pragma unroll
    for (int c = 0; c < 8; ++c) {
        int j = j0 + c;
        float v = fmaxf(fmaf((float)av[c], scb[j], shb[j]) + (float)hv[c], 0.f);
        vv[c] = v;
        mx = fmaxf(mx, v);          // relu'd: v >= 0
        o[c] = (__bf16)v;
    }
    ((bf16x8*)hout)[idx] = o;

    // group max across the 4 threads sharing cols [ks*32, ks*32+32)
    mx = fmaxf(mx, __shfl_xor(mx, 1));
    mx = fmaxf(mx, __shfl_xor(mx, 2));
    unsigned int em = (__float_as_uint(mx) >> 23) & 0xffu;
    unsigned int eb;
    float sinv;
    if (em < 7) { eb = 0; sinv = 0.f; }
    else { eb = em - 6; sinv = __uint_as_float((254 - eb) << 23); }
    if ((tid & 3) == 0) hsc[(size_t)(idx >> 4) * 4 + (sub >> 2)] = (unsigned char)eb;
    uint2 pk;
    pk.x = 0; pk.y = 0;
#pragma unroll
    for (int c = 0; c < 4; ++c) {
        unsigned int q0 = (unsigned int)rintf(fminf(fmaf(vv[c], sinv, 128.f), 255.f));
        unsigned int q1 = (unsigned int)rintf(fminf(fmaf(vv[4 + c], sinv, 128.f), 255.f));
        pk.x |= q0 << (8 * c);
        pk.y |= q1 << (8 * c);
    }
    // fragment-contiguous position: P = (ks>>1)*64 + q*16 + (ks&1)*8, ks=sub>>2, q=sub&3
    unsigned wpos = ((sub >> 3) & 1) * 64 + (sub & 3) * 16 + ((sub >> 2) & 1) * 8;
    *(uint2*)&h8[(size_t)(idx >> 4) * 128 + wpos] = pk;
}

extern "C" void kernel_launch(void* const* d_in, const int* in_sizes, int n_in,
                              void* d_out, int out_size, void* d_ws, size_t ws_size,
                              hipStream_t stream) {
    const float* x = (const float*)d_in[0];
    const float* ew = (const float*)d_in[1];
    const float* Win = (const float*)d_in[2];
    const float* bin = (const float*)d_in[3];
    const float* convW = (const float*)d_in[4];
    const float* gamma = (const float*)d_in[5];
    const float* bbeta = (const float*)d_in[6];
    const float* Wout = (const float*)d_in[7];
    const float* bout = (const float*)d_in[8];
    const int* erow = (const int*)d_in[9];
    const int* ecol = (const int*)d_in[10];
    float* out = (float*)d_out;

    char* wsp = (char*)d_ws;
    size_t off = 0;
    auto alloc = [&](size_t bytes) -> void* {
        void* p = wsp + off;
        off += (bytes + 255) & ~(size_t)255;
        return p;
    };
    __bf16* x0 = (__bf16*)alloc((size_t)NN * DH * 2);
    __bf16* h = (__bf16*)alloc((size_t)NN * DH * 2);
    __bf16* a = (__bf16*)alloc((size_t)NN * DH * 2);
    unsigned char* x08 = (unsigned char*)alloc((size_t)NN * DH);
    unsigned char* h8 = (unsigned char*)alloc((size_t)NN * DH);
    unsigned char* x0sc = (unsigned char*)alloc((size_t)NN * 4);
    unsigned char* hsc = (unsigned char*)alloc((size_t)NN * 4);
    int* rp = (int*)alloc((NN + 1) * 4);
    // zero-init region: cnt | fil | stats32 as ONE memset
    size_t zero_bytes = (size_t)NN * 4 + (size_t)NN * 4 + (size_t)NL * NSLOT * 256 * 4;
    int* cnt = (int*)alloc(zero_bytes);
    int* fil = cnt + NN;
    float* stats32 = (float*)(fil + NN);
    int2* ep = (int2*)alloc((size_t)EE * 8);
    int* part = (int*)alloc(256 * 4);
    __bf16* Bhi = (__bf16*)alloc((size_t)(NL + 1) * DH * DH * 2);
    __bf16* Blo = (__bf16*)alloc((size_t)(NL + 1) * DH * DH * 2);
    __bf16* Bohi = (__bf16*)alloc((size_t)DH * 48 * 2);
    __bf16* Bolo = (__bf16*)alloc((size_t)DH * 48 * 2);

    hipMemsetAsync(cnt, 0, zero_bytes, stream);

    k_hist<<<3125, 256, 0, stream>>>(erow, cnt);
    k_scan1<<<196, 512, 0, stream>>>(cnt, rp, part);
    k_scan2<<<1, 256, 0, stream>>>(part, 196);
    k_scan3<<<196, 512, 0, stream>>>(rp, part);
    k_fill<<<3125, 256, 0, stream>>>(erow, ecol, ew, rp, fil, ep);

    k_prep_w<<<NL + 1, 256, 0, stream>>>(convW, Win, Bhi, Blo);
    k_prep_out<<<1, 256, 0, stream>>>(Wout, Bohi, Bolo);

    k_lin_in<<<GEMM_GRID, 256, 0, stream>>>(x, Bhi + (size_t)NL * DH * DH, Blo + (size_t)NL * DH * DH, bin, x0);
    k_cvt8<<<1563, 256, 0, stream>>>(x0, x08, x0sc);

    for (int l = 0; l < NL; ++l) {
        const unsigned char* hin8 = (l == 0) ? x08 : h8;
        const unsigned char* hinsc = (l == 0) ? x0sc : hsc;
        const __bf16* hin = (l == 0) ? x0 : h;
        float* st = stats32 + (size_t)l * NSLOT * 256;
        k_spmm_gemm<<<SG_GRID, 512, 0, stream>>>(hin8, hinsc, x08, x0sc, rp, ep, a,
                                                 Bhi + (size_t)l * DH * DH, Blo + (size_t)l * DH * DH, st);
        k_update<<<6250, 256, 0, stream>>>(a, hin, h, h8, hsc, st, gamma + l * DH, bbeta + l * DH);
    }
    k_gemm_out<<<GEMM_GRID, 256, 0, stream>>>(h, Bohi, Bolo, bout, out);
}

// Round 8
// 1173.616 us; speedup vs baseline: 1.3199x; 1.0724x over previous
//
#include <hip/hip_runtime.h>
#include <math.h>

#define NN 100000
#define EE 800000
#define DH 128
#define NL 16
#define GEMM_GRID 1563
#define SG_GRID 782      // ceil(100000 / 128) for 8-wave spmm_gemm blocks
#define NSLOT 32
#define WROWS 12500      // NN/8 row-window per XCD for k_fill

typedef __bf16 bf16x8 __attribute__((ext_vector_type(8)));
typedef float f32x4 __attribute__((ext_vector_type(4)));

// ---------------- CSR build ----------------
__global__ void k_hist(const int* __restrict__ row, int* __restrict__ cnt) {
    int e = blockIdx.x * 256 + threadIdx.x;
    if (e < EE) atomicAdd(&cnt[row[e]], 1);
}

__global__ void k_scan1(const int* __restrict__ cnt, int* __restrict__ rp, int* __restrict__ part) {
    __shared__ int buf[512];
    int tid = threadIdx.x;
    int i = blockIdx.x * 512 + tid;
    int v = (i < NN) ? cnt[i] : 0;
    buf[tid] = v;
    __syncthreads();
    for (int off = 1; off < 512; off <<= 1) {
        int x = (tid >= off) ? buf[tid - off] : 0;
        __syncthreads();
        buf[tid] += x;
        __syncthreads();
    }
    if (i < NN) rp[i] = buf[tid] - v;
    if (tid == 511) part[blockIdx.x] = buf[511];
}

__global__ void k_scan2(int* __restrict__ part, int nparts) {
    __shared__ int buf[256];
    int tid = threadIdx.x;
    int v = (tid < nparts) ? part[tid] : 0;
    buf[tid] = v;
    __syncthreads();
    for (int off = 1; off < 256; off <<= 1) {
        int x = (tid >= off) ? buf[tid - off] : 0;
        __syncthreads();
        buf[tid] += x;
        __syncthreads();
    }
    if (tid < nparts) part[tid] = buf[tid] - v;
}

__global__ void k_scan3(int* __restrict__ rp, const int* __restrict__ part) {
    int i = blockIdx.x * 512 + threadIdx.x;
    if (i < NN) rp[i] += part[blockIdx.x];
    if (i == 0) rp[NN] = EE;
}

// ---------------- degree-sort permutation (counting sort, 64 bins, DESCENDING for LPT) ----------------
__global__ void k_dhist(const int* __restrict__ cnt, int* __restrict__ dbin) {
    __shared__ int lb[64];
    int tid = threadIdx.x;
    if (tid < 64) lb[tid] = 0;
    __syncthreads();
    int i = blockIdx.x * 256 + tid;
    if (i < NN) {
        int d = cnt[i];
        if (d > 63) d = 63;
        atomicAdd(&lb[63 - d], 1);
    }
    __syncthreads();
    if (tid < 64 && lb[tid]) atomicAdd(&dbin[tid], lb[tid]);
}

__global__ void k_pscan(const int* __restrict__ dbin, int* __restrict__ dpre) {
    if (threadIdx.x == 0) {
        int s = 0;
        for (int i = 0; i < 64; ++i) { dpre[i] = s; s += dbin[i]; }
    }
}

__global__ void k_pscatter(const int* __restrict__ cnt, const int* __restrict__ dpre,
                           int* __restrict__ dfil, int* __restrict__ perm) {
    __shared__ int lcnt[64], lbase[64];
    int tid = threadIdx.x;
    if (tid < 64) lcnt[tid] = 0;
    __syncthreads();
    int i = blockIdx.x * 256 + tid;
    int b = 0, loc = 0;
    bool ok = (i < NN);
    if (ok) {
        int d = cnt[i];
        if (d > 63) d = 63;
        b = 63 - d;
        loc = atomicAdd(&lcnt[b], 1);
    }
    __syncthreads();
    if (tid < 64 && lcnt[tid]) lbase[tid] = atomicAdd(&dfil[tid], lcnt[tid]);
    __syncthreads();
    if (ok) perm[dpre[b] + lbase[b] + loc] = i;
}

// ---------------- k_fill, XCD-row-windowed ----------------
// block b: window w = b&7 (round-robin dispatch -> XCD w), edge chunk b>>3.
// All writes to ep window w (contiguous ~800KB, since rp is sorted) come from one
// XCD -> its L2 owns the lines -> full-line evictions instead of cross-XCD
// partial-line RMW (R7 counters: 53.6 MB WRITE for a 6.4 MB array). fil atomics
// become XCD-local too. w prescaled by (1-ALPHA)=0.9.
__global__ void k_fill(const int* __restrict__ row, const int* __restrict__ col,
                       const float* __restrict__ w, const int* __restrict__ rp,
                       int* __restrict__ fil, int2* __restrict__ ep) {
    int b = blockIdx.x;
    int win = b & 7;
    int e = (b >> 3) * 256 + threadIdx.x;
    if (e >= EE) return;
    int r = row[e];
    if (r / WROWS != win) return;
    int pos = rp[r] + atomicAdd(&fil[r], 1);
    ep[pos] = make_int2(col[e], __float_as_int(0.9f * w[e]));
}

// ---------------- weight prep: split hi/lo bf16 + swizzle to MFMA fragment order ----------------
// frag[t][ks][lane][e] = M[k][j], j = t*16 + (lane&15), k = ks*32 + (lane>>4)*8 + e
__global__ void k_prep_w(const float* __restrict__ convW, const float* __restrict__ Win,
                         __bf16* __restrict__ Bhi, __bf16* __restrict__ Blo) {
    int l = blockIdx.x;
    const float* W;
    float beta, ob;
    if (l < NL) {
        beta = logf(0.5f / (float)(l + 1) + 1.0f);
        ob = 1.0f - beta;
        W = convW + (size_t)l * DH * DH;
    } else {
        beta = 1.0f;
        ob = 0.0f;
        W = Win;
    }
    __bf16* bh = Bhi + (size_t)l * DH * DH;
    __bf16* bl = Blo + (size_t)l * DH * DH;
    for (int i = threadIdx.x; i < DH * DH; i += 256) {
        int k = i >> 7, j = i & 127;
        float v = beta * W[i] + ((k == j) ? ob : 0.f);
        __bf16 hv = (__bf16)v;
        int t = j >> 4, n = j & 15, ks = k >> 5, quad = (k >> 3) & 3, e = k & 7;
        int off = ((t * 4 + ks) * 64 + quad * 16 + n) * 8 + e;
        bh[off] = hv;
        bl[off] = (__bf16)(v - (float)hv);
    }
}

__global__ void k_prep_out(const float* __restrict__ Wout, __bf16* __restrict__ Bhi, __bf16* __restrict__ Blo) {
    for (int i = threadIdx.x; i < DH * 48; i += 256) {
        int k = i / 48, j = i % 48;
        float v = (j < 40) ? Wout[k * 40 + j] : 0.f;
        __bf16 hv = (__bf16)v;
        int t = j >> 4, n = j & 15, ks = k >> 5, quad = (k >> 3) & 3, e = k & 7;
        int off = ((t * 4 + ks) * 64 + quad * 16 + n) * 8 + e;
        Bhi[off] = hv;
        Blo[off] = (__bf16)(v - (float)hv);
    }
}

__device__ inline void split8(const float* p, bf16x8& hi, bf16x8& lo) {
    f32x4 v0 = *(const f32x4*)p;
    f32x4 v1 = *(const f32x4*)(p + 4);
#pragma unroll
    for (int j = 0; j < 4; ++j) {
        __bf16 h0 = (__bf16)v0[j];
        hi[j] = h0;
        lo[j] = (__bf16)(v0[j] - (float)h0);
        __bf16 h1 = (__bf16)v1[j];
        hi[4 + j] = h1;
        lo[4 + j] = (__bf16)(v1[j] - (float)h1);
    }
}

#define MFMA(a, b, c) __builtin_amdgcn_mfma_f32_16x16x32_bf16(a, b, c, 0, 0, 0)

// ---------------- int8 group quantization (32-feature groups, pow2 scale) ----------------
__device__ inline float dec_scale(unsigned int sc4, int ks) {
    return __uint_as_float(((sc4 >> (8 * ks)) & 0xffu) << 23);
}

#define DEC_DW(dw, wsv, a0, a1, a2, a3)                         \
    {                                                           \
        a0 = fmaf(wsv, (float)((dw)&0xffu), a0);                \
        a1 = fmaf(wsv, (float)(((dw) >> 8) & 0xffu), a1);       \
        a2 = fmaf(wsv, (float)(((dw) >> 16) & 0xffu), a2);      \
        a3 = fmaf(wsv, (float)((dw) >> 24), a3);                \
    }

#define EDGE_FMA(S4, W, RA, RB)                                       \
    {                                                                 \
        float _w = (W);                                               \
        float _w0 = _w * dec_scale(S4, 0);                            \
        float _w1 = _w * dec_scale(S4, 1);                            \
        float _w2 = _w * dec_scale(S4, 2);                            \
        float _w3 = _w * dec_scale(S4, 3);                            \
        sw0 += _w0; sw1 += _w1; sw2 += _w2; sw3 += _w3;               \
        DEC_DW((RA).x, _w0, acc[0][0], acc[0][1], acc[0][2], acc[0][3]); \
        DEC_DW((RA).y, _w0, acc[0][4], acc[0][5], acc[0][6], acc[0][7]); \
        DEC_DW((RA).z, _w1, acc[1][0], acc[1][1], acc[1][2], acc[1][3]); \
        DEC_DW((RA).w, _w1, acc[1][4], acc[1][5], acc[1][6], acc[1][7]); \
        DEC_DW((RB).x, _w2, acc[2][0], acc[2][1], acc[2][2], acc[2][3]); \
        DEC_DW((RB).y, _w2, acc[2][4], acc[2][5], acc[2][6], acc[2][7]); \
        DEC_DW((RB).z, _w3, acc[3][0], acc[3][1], acc[3][2], acc[3][3]); \
        DEC_DW((RB).w, _w3, acc[3][4], acc[3][5], acc[3][6], acc[3][7]); \
    }

// x0 bf16 -> int8 groups (one thread per 32-feature group), fragment-contiguous layout
__global__ void k_cvt8(const __bf16* __restrict__ src, unsigned char* __restrict__ q8,
                       unsigned char* __restrict__ sc) {
    int t = blockIdx.x * 256 + threadIdx.x;
    if (t >= NN * 4) return;
    int node = t >> 2, ks = t & 3;
    const __bf16* p = src + (size_t)node * DH + ks * 32;
    float v[32];
    float mx = 0.f;
#pragma unroll
    for (int i = 0; i < 4; ++i) {
        bf16x8 b = *(const bf16x8*)(p + i * 8);
#pragma unroll
        for (int c = 0; c < 8; ++c) {
            float f = (float)b[c];
            v[i * 8 + c] = f;
            mx = fmaxf(mx, fabsf(f));
        }
    }
    unsigned int em = (__float_as_uint(mx) >> 23) & 0xffu;
    unsigned int eb;
    float sinv;
    if (em < 7) { eb = 0; sinv = 0.f; }
    else { eb = em - 6; sinv = __uint_as_float((254 - eb) << 23); }
    sc[(size_t)node * 4 + ks] = (unsigned char)eb;
    unsigned char* bp = q8 + (size_t)node * 128 + (ks >> 1) * 64 + (ks & 1) * 8;
#pragma unroll
    for (int q = 0; q < 4; ++q) {
        uint2 w;
        w.x = 0; w.y = 0;
#pragma unroll
        for (int c = 0; c < 4; ++c) {
            unsigned int q0 = (unsigned int)rintf(fminf(fmaf(v[q * 8 + c], sinv, 128.f), 255.f));
            unsigned int q1 = (unsigned int)rintf(fminf(fmaf(v[q * 8 + 4 + c], sinv, 128.f), 255.f));
            w.x |= q0 << (8 * c);
            w.y |= q1 << (8 * c);
        }
        *(uint2*)(bp + q * 16) = w;
    }
}

// ---------------- FUSED SpMM + mix + layer GEMM (int8, pipelined, degree-sorted) ----------------
// Node order is PERMUTED by descending degree: the gather loop's trip count is
// max over the 16 nodes of a lane-group; Poisson(8) degrees make E[max of 16]
// ~14-15 edges vs mean 8 (~45% divergence waste). Sorted order makes the 16
// near-uniform. Arithmetic per node is identical; only the wave->node mapping
// changes. aout rows are still written whole (no write amplification).
__global__ __launch_bounds__(512, 4) void k_spmm_gemm(const unsigned char* __restrict__ hin8,
                                                      const unsigned char* __restrict__ hinsc,
                                                      const unsigned char* __restrict__ x08,
                                                      const unsigned char* __restrict__ x0sc,
                                                      const int* __restrict__ rp, const int2* __restrict__ ep,
                                                      const int* __restrict__ perm,
                                                      __bf16* __restrict__ aout,
                                                      const __bf16* __restrict__ Bhi, const __bf16* __restrict__ Blo,
                                                      float* __restrict__ stats32) {
    __shared__ __bf16 Bs[2 * DH * DH];  // [hi|lo] in MFMA fragment order
    __shared__ float red[2][8][DH];
    int tid = threadIdx.x;
    {
        const f32x4* sh = (const f32x4*)Bhi;
        const f32x4* sl = (const f32x4*)Blo;
        f32x4* dh = (f32x4*)Bs;
        f32x4* dl = (f32x4*)(Bs + DH * DH);
#pragma unroll
        for (int i = 0; i < 4; ++i) {
            dh[tid + i * 512] = sh[tid + i * 512];
            dl[tid + i * 512] = sl[tid + i * 512];
        }
    }
    // no sync yet: gather phase doesn't touch Bs; sync sits right before MFMA.

    int wave = tid >> 6, lane = tid & 63;
    int n = lane & 15, quad = lane >> 4;
    int r0 = blockIdx.x * 128 + wave * 16;
    int idx = r0 + n;
    int pidx = (idx < NN) ? idx : (NN - 1);
    int node = perm[pidx];           // actual node id (valid always)

    float acc[4][8];
#pragma unroll
    for (int ks = 0; ks < 4; ++ks)
#pragma unroll
        for (int c = 0; c < 8; ++c) acc[ks][c] = 0.f;
    float sw0 = 0.f, sw1 = 0.f, sw2 = 0.f, sw3 = 0.f;

    // x0 self-term loads
    unsigned xs4 = *(const unsigned*)&x0sc[(size_t)node * 4];
    const unsigned char* xb = x08 + (size_t)node * 128 + quad * 16;
    uint4 xa = *(const uint4*)xb;
    uint4 xc = *(const uint4*)(xb + 64);

    int s = 0, e = 0;
    if (idx < NN) { s = rp[node]; e = rp[node + 1]; }
    int cnt = e - s;
    int npairs = cnt >> 1;

    const unsigned char* hb = hin8 + quad * 16;

    int2 cP0, cP1, fP0, fP1;
    unsigned cS0, cS1;
    uint4 cA0, cB0, cA1, cB1;
    if (npairs > 0) {
        cP0 = ep[s]; cP1 = ep[s + 1];
        cS0 = *(const unsigned*)&hinsc[(size_t)cP0.x * 4];
        cS1 = *(const unsigned*)&hinsc[(size_t)cP1.x * 4];
        const unsigned char* b0 = hb + (size_t)cP0.x * 128;
        const unsigned char* b1 = hb + (size_t)cP1.x * 128;
        cA0 = *(const uint4*)b0; cB0 = *(const uint4*)(b0 + 64);
        cA1 = *(const uint4*)b1; cB1 = *(const uint4*)(b1 + 64);
        int jf = s + 2; if (jf > EE - 2) jf = EE - 2;
        fP0 = ep[jf]; fP1 = ep[jf + 1];
    }

    EDGE_FMA(xs4, 0.1f, xa, xc);   // weight 0.1 on x0 (alpha mix)

    int j = s;
    for (int it = 0; it < npairs; ++it) {
        // stage 1: ep prefetch for pair it+2 (clamped speculative)
        int j2 = j + 4; if (j2 > EE - 2) j2 = EE - 2;
        int2 eN0 = ep[j2], eN1 = ep[j2 + 1];
        // stage 2: scales + rows for pair it+1
        unsigned tS0 = *(const unsigned*)&hinsc[(size_t)fP0.x * 4];
        unsigned tS1 = *(const unsigned*)&hinsc[(size_t)fP1.x * 4];
        const unsigned char* b0 = hb + (size_t)fP0.x * 128;
        const unsigned char* b1 = hb + (size_t)fP1.x * 128;
        uint4 tA0 = *(const uint4*)b0, tB0 = *(const uint4*)(b0 + 64);
        uint4 tA1 = *(const uint4*)b1, tB1 = *(const uint4*)(b1 + 64);
        // stage 3: fma pair it
        EDGE_FMA(cS0, __int_as_float(cP0.y), cA0, cB0);
        EDGE_FMA(cS1, __int_as_float(cP1.y), cA1, cB1);
        cP0 = fP0; cP1 = fP1; fP0 = eN0; fP1 = eN1;
        cS0 = tS0; cS1 = tS1;
        cA0 = tA0; cB0 = tB0; cA1 = tA1; cB1 = tB1;
        j += 2;
    }
    if (cnt & 1) {
        int2 pe = ep[e - 1];
        unsigned s4 = *(const unsigned*)&hinsc[(size_t)pe.x * 4];
        const unsigned char* bp = hb + (size_t)pe.x * 128;
        uint4 ra = *(const uint4*)bp, rb = *(const uint4*)(bp + 64);
        EDGE_FMA(s4, __int_as_float(pe.y), ra, rb);
    }

    // bias correction (u8 -> u8-128) + bf16 A fragments
    bf16x8 av[4];
    {
        float sws[4] = {sw0, sw1, sw2, sw3};
#pragma unroll
        for (int ks = 0; ks < 4; ++ks)
#pragma unroll
            for (int c = 0; c < 8; ++c)
                av[ks][c] = (__bf16)(acc[ks][c] - 128.0f * sws[ks]);
    }

    // permuted output rows for this lane's C-fragment: perm[r0+quad*4+r],
    // held by lane (quad*4+r) (its n == quad*4+r).
    int prow[4];
#pragma unroll
    for (int r = 0; r < 4; ++r) prow[r] = __shfl(node, quad * 4 + r);

    __syncthreads();  // Bs staging complete across all waves

    f32x4 gacc[8];
#pragma unroll
    for (int t = 0; t < 8; ++t) gacc[t] = (f32x4){0.f, 0.f, 0.f, 0.f};

#pragma unroll
    for (int ks = 0; ks < 4; ++ks) {
#pragma unroll
        for (int t = 0; t < 8; ++t) {
            int base = ((t * 4 + ks) * 64 + lane) * 8;
            bf16x8 bh = *(const bf16x8*)&Bs[base];
            bf16x8 bl = *(const bf16x8*)&Bs[DH * DH + base];
            gacc[t] = MFMA(av[ks], bh, gacc[t]);
            gacc[t] = MFMA(av[ks], bl, gacc[t]);
        }
    }

#pragma unroll
    for (int t = 0; t < 8; ++t) {
        float sm = 0.f, qq = 0.f;
#pragma unroll
        for (int r = 0; r < 4; ++r) {
            int row = r0 + quad * 4 + r;   // pre-perm index: validity mask
            float v = gacc[t][r];
            if (row < NN) {
                aout[(size_t)prow[r] * DH + t * 16 + n] = (__bf16)v;
                sm += v;
                qq += v * v;
            }
        }
        sm += __shfl_xor(sm, 16); sm += __shfl_xor(sm, 32);
        qq += __shfl_xor(qq, 16); qq += __shfl_xor(qq, 32);
        if (quad == 0) {
            red[0][wave][t * 16 + n] = sm;
            red[1][wave][t * 16 + n] = qq;
        }
    }
    __syncthreads();
    if (tid < 256) {
        int which = tid >> 7, jj = tid & 127;
        float tot = 0.f;
#pragma unroll
        for (int w = 0; w < 8; ++w) tot += red[which][w][jj];
        atomicAdd(&stats32[(size_t)(blockIdx.x & (NSLOT - 1)) * 256 + tid], tot);
    }
}

// ---------------- input GEMM: x0 = relu(X @ Win + bin), fp32 A split on the fly, B in LDS ----------------
__global__ __launch_bounds__(256) void k_lin_in(const float* __restrict__ X,
                                                const __bf16* __restrict__ Bhi, const __bf16* __restrict__ Blo,
                                                const float* __restrict__ bin, __bf16* __restrict__ x0) {
    __shared__ __bf16 Bs[2 * DH * DH];
    int tid = threadIdx.x;
    {
        const f32x4* sh = (const f32x4*)Bhi;
        const f32x4* sl = (const f32x4*)Blo;
        f32x4* dh = (f32x4*)Bs;
        f32x4* dl = (f32x4*)(Bs + DH * DH);
#pragma unroll
        for (int i = 0; i < 8; ++i) {
            dh[tid + i * 256] = sh[tid + i * 256];
            dl[tid + i * 256] = sl[tid + i * 256];
        }
    }
    __syncthreads();

    int wave = tid >> 6, lane = tid & 63;
    int n = lane & 15, quad = lane >> 4;
    int r0 = blockIdx.x * 64 + wave * 16;
    int arow = r0 + n;
    if (arow > NN - 1) arow = NN - 1;
    const float* pa = X + (size_t)arow * DH + quad * 8;

    f32x4 acc[8];
#pragma unroll
    for (int t = 0; t < 8; ++t) acc[t] = (f32x4){0.f, 0.f, 0.f, 0.f};

#pragma unroll
    for (int ks = 0; ks < 4; ++ks) {
        bf16x8 ah, al;
        split8(pa + ks * 32, ah, al);
#pragma unroll
        for (int t = 0; t < 8; ++t) {
            int base = ((t * 4 + ks) * 64 + lane) * 8;
            bf16x8 bh = *(const bf16x8*)&Bs[base];
            bf16x8 bl = *(const bf16x8*)&Bs[DH * DH + base];
            acc[t] = MFMA(ah, bh, acc[t]);
            acc[t] = MFMA(al, bh, acc[t]);
            acc[t] = MFMA(ah, bl, acc[t]);
        }
    }

#pragma unroll
    for (int t = 0; t < 8; ++t) {
        float bj = bin[t * 16 + n];
#pragma unroll
        for (int r = 0; r < 4; ++r) {
            int row = r0 + quad * 4 + r;
            if (row < NN) {
                float v = fmaxf(acc[t][r] + bj, 0.f);
                x0[(size_t)row * DH + t * 16 + n] = (__bf16)v;
            }
        }
    }
}

// ---------------- output GEMM: out = h @ Wout + bout (3 tiles of 16 cols), B in LDS ----------------
__global__ __launch_bounds__(256) void k_gemm_out(const __bf16* __restrict__ A,
                                                  const __bf16* __restrict__ Bhi, const __bf16* __restrict__ Blo,
                                                  const float* __restrict__ bout, float* __restrict__ out) {
    __shared__ __bf16 Bs[2 * 48 * DH];
    int tid = threadIdx.x;
    {
        const f32x4* sh = (const f32x4*)Bhi;
        const f32x4* sl = (const f32x4*)Blo;
        f32x4* dh = (f32x4*)Bs;
        f32x4* dl = (f32x4*)(Bs + 48 * DH);
#pragma unroll
        for (int i = 0; i < 3; ++i) {
            dh[tid + i * 256] = sh[tid + i * 256];
            dl[tid + i * 256] = sl[tid + i * 256];
        }
    }
    __syncthreads();

    int wave = tid >> 6, lane = tid & 63;
    int n = lane & 15, quad = lane >> 4;
    int r0 = blockIdx.x * 64 + wave * 16;
    int arow = r0 + n;
    if (arow > NN - 1) arow = NN - 1;
    const __bf16* pa = A + (size_t)arow * DH + quad * 8;

    f32x4 acc[3];
#pragma unroll
    for (int t = 0; t < 3; ++t) acc[t] = (f32x4){0.f, 0.f, 0.f, 0.f};

#pragma unroll
    for (int ks = 0; ks < 4; ++ks) {
        bf16x8 av = *(const bf16x8*)(pa + ks * 32);
#pragma unroll
        for (int t = 0; t < 3; ++t) {
            int base = ((t * 4 + ks) * 64 + lane) * 8;
            bf16x8 bh = *(const bf16x8*)&Bs[base];
            bf16x8 bl = *(const bf16x8*)&Bs[48 * DH + base];
            acc[t] = MFMA(av, bh, acc[t]);
            acc[t] = MFMA(av, bl, acc[t]);
        }
    }

#pragma unroll
    for (int t = 0; t < 3; ++t) {
        int j = t * 16 + n;
        float bj = (j < 40) ? bout[j] : 0.f;
#pragma unroll
        for (int r = 0; r < 4; ++r) {
            int row = r0 + quad * 4 + r;
            if (row < NN && j < 40) out[(size_t)row * 40 + j] = acc[t][r] + bj;
        }
    }
}

// ---------------- fused slot-reduce + BN-finalize + update + int8 re-encode ----------------
__global__ __launch_bounds__(256) void k_update(const __bf16* __restrict__ a, const __bf16* __restrict__ hin,
                                                __bf16* __restrict__ hout,
                                                unsigned char* __restrict__ h8, unsigned char* __restrict__ hsc,
                                                const float* __restrict__ stats32,
                                                const float* __restrict__ gamma, const float* __restrict__ bbeta) {
    __shared__ float scb[DH], shb[DH];
    int tid = threadIdx.x;
    if (tid < DH) {
        float s = 0.f, q = 0.f;
#pragma unroll
        for (int sl = 0; sl < NSLOT; ++sl) {
            s += stats32[(size_t)sl * 256 + tid];
            q += stats32[(size_t)sl * 256 + 128 + tid];
        }
        float mu = s * (1.0f / NN);
        float var = q * (1.0f / NN) - mu * mu;
        if (var < 0.f) var = 0.f;
        float sc = gamma[tid] * rsqrtf(var + 1e-5f);
        scb[tid] = sc;
        shb[tid] = bbeta[tid] - mu * sc;
    }
    __syncthreads();

    int idx = blockIdx.x * 256 + tid;
    int sub = idx & 15;
    int j0 = sub * 8;
    bf16x8 av = ((const bf16x8*)a)[idx];
    bf16x8 hv = ((const bf16x8*)hin)[idx];
    bf16x8 o;
    float vv[8];
    float mx = 0.f;
#pragma unroll
    for (int c = 0; c < 8; ++c) {
        int j = j0 + c;
        float v = fmaxf(fmaf((float)av[c], scb[j], shb[j]) + (float)hv[c], 0.f);
        vv[c] = v;
        mx = fmaxf(mx, v);          // relu'd: v >= 0
        o[c] = (__bf16)v;
    }
    ((bf16x8*)hout)[idx] = o;

    // group max across the 4 threads sharing cols [ks*32, ks*32+32)
    mx = fmaxf(mx, __shfl_xor(mx, 1));
    mx = fmaxf(mx, __shfl_xor(mx, 2));
    unsigned int em = (__float_as_uint(mx) >> 23) & 0xffu;
    unsigned int eb;
    float sinv;
    if (em < 7) { eb = 0; sinv = 0.f; }
    else { eb = em - 6; sinv = __uint_as_float((254 - eb) << 23); }
    if ((tid & 3) == 0) hsc[(size_t)(idx >> 4) * 4 + (sub >> 2)] = (unsigned char)eb;
    uint2 pk;
    pk.x = 0; pk.y = 0;
#pragma unroll
    for (int c = 0; c < 4; ++c) {
        unsigned int q0 = (unsigned int)rintf(fminf(fmaf(vv[c], sinv, 128.f), 255.f));
        unsigned int q1 = (unsigned int)rintf(fminf(fmaf(vv[4 + c], sinv, 128.f), 255.f));
        pk.x |= q0 << (8 * c);
        pk.y |= q1 << (8 * c);
    }
    // fragment-contiguous position: P = (ks>>1)*64 + q*16 + (ks&1)*8, ks=sub>>2, q=sub&3
    unsigned wpos = ((sub >> 3) & 1) * 64 + (sub & 3) * 16 + ((sub >> 2) & 1) * 8;
    *(uint2*)&h8[(size_t)(idx >> 4) * 128 + wpos] = pk;
}

extern "C" void kernel_launch(void* const* d_in, const int* in_sizes, int n_in,
                              void* d_out, int out_size, void* d_ws, size_t ws_size,
                              hipStream_t stream) {
    const float* x = (const float*)d_in[0];
    const float* ew = (const float*)d_in[1];
    const float* Win = (const float*)d_in[2];
    const float* bin = (const float*)d_in[3];
    const float* convW = (const float*)d_in[4];
    const float* gamma = (const float*)d_in[5];
    const float* bbeta = (const float*)d_in[6];
    const float* Wout = (const float*)d_in[7];
    const float* bout = (const float*)d_in[8];
    const int* erow = (const int*)d_in[9];
    const int* ecol = (const int*)d_in[10];
    float* out = (float*)d_out;

    char* wsp = (char*)d_ws;
    size_t off = 0;
    auto alloc = [&](size_t bytes) -> void* {
        void* p = wsp + off;
        off += (bytes + 255) & ~(size_t)255;
        return p;
    };
    __bf16* x0 = (__bf16*)alloc((size_t)NN * DH * 2);
    __bf16* h = (__bf16*)alloc((size_t)NN * DH * 2);
    __bf16* a = (__bf16*)alloc((size_t)NN * DH * 2);
    unsigned char* x08 = (unsigned char*)alloc((size_t)NN * DH);
    unsigned char* h8 = (unsigned char*)alloc((size_t)NN * DH);
    unsigned char* x0sc = (unsigned char*)alloc((size_t)NN * 4);
    unsigned char* hsc = (unsigned char*)alloc((size_t)NN * 4);
    int* rp = (int*)alloc((NN + 1) * 4);
    int* perm = (int*)alloc((size_t)NN * 4);
    int* dpre = (int*)alloc(64 * 4);
    // zero-init region: cnt | fil | stats32 | dbin | dfil as ONE memset
    size_t zero_bytes = (size_t)NN * 4 + (size_t)NN * 4 + (size_t)NL * NSLOT * 256 * 4 + 128 * 4;
    int* cnt = (int*)alloc(zero_bytes);
    int* fil = cnt + NN;
    float* stats32 = (float*)(fil + NN);
    int* dbin = (int*)(stats32 + (size_t)NL * NSLOT * 256);
    int* dfil = dbin + 64;
    int2* ep = (int2*)alloc((size_t)EE * 8);
    int* part = (int*)alloc(256 * 4);
    __bf16* Bhi = (__bf16*)alloc((size_t)(NL + 1) * DH * DH * 2);
    __bf16* Blo = (__bf16*)alloc((size_t)(NL + 1) * DH * DH * 2);
    __bf16* Bohi = (__bf16*)alloc((size_t)DH * 48 * 2);
    __bf16* Bolo = (__bf16*)alloc((size_t)DH * 48 * 2);

    hipMemsetAsync(cnt, 0, zero_bytes, stream);

    k_hist<<<3125, 256, 0, stream>>>(erow, cnt);
    k_dhist<<<391, 256, 0, stream>>>(cnt, dbin);
    k_pscan<<<1, 64, 0, stream>>>(dbin, dpre);
    k_pscatter<<<391, 256, 0, stream>>>(cnt, dpre, dfil, perm);
    k_scan1<<<196, 512, 0, stream>>>(cnt, rp, part);
    k_scan2<<<1, 256, 0, stream>>>(part, 196);
    k_scan3<<<196, 512, 0, stream>>>(rp, part);
    k_fill<<<25000, 256, 0, stream>>>(erow, ecol, ew, rp, fil, ep);

    k_prep_w<<<NL + 1, 256, 0, stream>>>(convW, Win, Bhi, Blo);
    k_prep_out<<<1, 256, 0, stream>>>(Wout, Bohi, Bolo);

    k_lin_in<<<GEMM_GRID, 256, 0, stream>>>(x, Bhi + (size_t)NL * DH * DH, Blo + (size_t)NL * DH * DH, bin, x0);
    k_cvt8<<<1563, 256, 0, stream>>>(x0, x08, x0sc);

    for (int l = 0; l < NL; ++l) {
        const unsigned char* hin8 = (l == 0) ? x08 : h8;
        const unsigned char* hinsc = (l == 0) ? x0sc : hsc;
        const __bf16* hin = (l == 0) ? x0 : h;
        float* st = stats32 + (size_t)l * NSLOT * 256;
        k_spmm_gemm<<<SG_GRID, 512, 0, stream>>>(hin8, hinsc, x08, x0sc, rp, ep, perm, a,
                                                 Bhi + (size_t)l * DH * DH, Blo + (size_t)l * DH * DH, st);
        k_update<<<6250, 256, 0, stream>>>(a, hin, h, h8, hsc, st, gamma + l * DH, bbeta + l * DH);
    }
    k_gemm_out<<<GEMM_GRID, 256, 0, stream>>>(h, Bohi, Bolo, bout, out);
}

// Round 9
// 1154.279 us; speedup vs baseline: 1.3420x; 1.0168x over previous
//
#include <hip/hip_runtime.h>
#include <math.h>

#define NN 100000
#define EE 800000
#define DH 128
#define NL 16
#define GEMM_GRID 1563
#define SG_GRID 782      // ceil(100000 / 128) for 8-wave blocks
#define NSLOT 32
#define WROWS 12500      // NN/8 row-window per XCD for k_fill

typedef __bf16 bf16x8 __attribute__((ext_vector_type(8)));
typedef float f32x4 __attribute__((ext_vector_type(4)));

// ---------------- CSR build ----------------
__global__ void k_hist(const int* __restrict__ row, int* __restrict__ cnt) {
    int e = blockIdx.x * 256 + threadIdx.x;
    if (e < EE) atomicAdd(&cnt[row[e]], 1);
}

__global__ void k_scan1(const int* __restrict__ cnt, int* __restrict__ rp, int* __restrict__ part) {
    __shared__ int buf[512];
    int tid = threadIdx.x;
    int i = blockIdx.x * 512 + tid;
    int v = (i < NN) ? cnt[i] : 0;
    buf[tid] = v;
    __syncthreads();
    for (int off = 1; off < 512; off <<= 1) {
        int x = (tid >= off) ? buf[tid - off] : 0;
        __syncthreads();
        buf[tid] += x;
        __syncthreads();
    }
    if (i < NN) rp[i] = buf[tid] - v;
    if (tid == 511) part[blockIdx.x] = buf[511];
}

__global__ void k_scan2(int* __restrict__ part, int nparts) {
    __shared__ int buf[256];
    int tid = threadIdx.x;
    int v = (tid < nparts) ? part[tid] : 0;
    buf[tid] = v;
    __syncthreads();
    for (int off = 1; off < 256; off <<= 1) {
        int x = (tid >= off) ? buf[tid - off] : 0;
        __syncthreads();
        buf[tid] += x;
        __syncthreads();
    }
    if (tid < nparts) part[tid] = buf[tid] - v;
}

__global__ void k_scan3(int* __restrict__ rp, const int* __restrict__ part) {
    int i = blockIdx.x * 512 + threadIdx.x;
    if (i < NN) rp[i] += part[blockIdx.x];
    if (i == 0) rp[NN] = EE;
}

// ---------------- degree-sort permutation (counting sort, 64 bins, DESCENDING for LPT) ----------------
__global__ void k_dhist(const int* __restrict__ cnt, int* __restrict__ dbin) {
    __shared__ int lb[64];
    int tid = threadIdx.x;
    if (tid < 64) lb[tid] = 0;
    __syncthreads();
    int i = blockIdx.x * 256 + tid;
    if (i < NN) {
        int d = cnt[i];
        if (d > 63) d = 63;
        atomicAdd(&lb[63 - d], 1);
    }
    __syncthreads();
    if (tid < 64 && lb[tid]) atomicAdd(&dbin[tid], lb[tid]);
}

__global__ void k_pscan(const int* __restrict__ dbin, int* __restrict__ dpre) {
    if (threadIdx.x == 0) {
        int s = 0;
        for (int i = 0; i < 64; ++i) { dpre[i] = s; s += dbin[i]; }
    }
}

__global__ void k_pscatter(const int* __restrict__ cnt, const int* __restrict__ dpre,
                           int* __restrict__ dfil, int* __restrict__ perm) {
    __shared__ int lcnt[64], lbase[64];
    int tid = threadIdx.x;
    if (tid < 64) lcnt[tid] = 0;
    __syncthreads();
    int i = blockIdx.x * 256 + tid;
    int b = 0, loc = 0;
    bool ok = (i < NN);
    if (ok) {
        int d = cnt[i];
        if (d > 63) d = 63;
        b = 63 - d;
        loc = atomicAdd(&lcnt[b], 1);
    }
    __syncthreads();
    if (tid < 64 && lcnt[tid]) lbase[tid] = atomicAdd(&dfil[tid], lcnt[tid]);
    __syncthreads();
    if (ok) perm[dpre[b] + lbase[b] + loc] = i;
}

// iperm[perm[i]] = i; cnt2[i] = degree of i-th sorted node (for permuted-space rp)
__global__ void k_iperm(const int* __restrict__ perm, const int* __restrict__ cnt,
                        int* __restrict__ iperm, int* __restrict__ cnt2) {
    int i = blockIdx.x * 256 + threadIdx.x;
    if (i < NN) {
        int p = perm[i];
        iperm[p] = i;
        cnt2[i] = cnt[p];
    }
}

// ---------------- k_fill: builds CSR directly in PERMUTED space, XCD-row-windowed ----------------
// The whole layer pipeline runs in degree-sorted node space (zero perm lookups,
// all streams sequential); only CSR build and the pipeline edges touch perm/iperm.
// iperm is 400KB -> L2-resident, the per-edge translations are cheap.
// Window w = b&7 (round-robin dispatch -> XCD w) owns permuted rows [w*12500, ..):
// contiguous ep region per XCD -> full-line evictions, no cross-XCD RMW (R8-verified).
__global__ void k_fill(const int* __restrict__ row, const int* __restrict__ col,
                       const float* __restrict__ w, const int* __restrict__ rp,
                       const int* __restrict__ iperm,
                       int* __restrict__ fil, int2* __restrict__ ep) {
    int b = blockIdx.x;
    int win = b & 7;
    int e = (b >> 3) * 256 + threadIdx.x;
    if (e >= EE) return;
    int r = iperm[row[e]];
    if (r / WROWS != win) return;
    int pos = rp[r] + atomicAdd(&fil[r], 1);
    ep[pos] = make_int2(iperm[col[e]], __float_as_int(0.9f * w[e]));
}

// ---------------- weight prep: split hi/lo bf16 + swizzle to MFMA fragment order ----------------
__global__ void k_prep_w(const float* __restrict__ convW, const float* __restrict__ Win,
                         __bf16* __restrict__ Bhi, __bf16* __restrict__ Blo) {
    int l = blockIdx.x;
    const float* W;
    float beta, ob;
    if (l < NL) {
        beta = logf(0.5f / (float)(l + 1) + 1.0f);
        ob = 1.0f - beta;
        W = convW + (size_t)l * DH * DH;
    } else {
        beta = 1.0f;
        ob = 0.0f;
        W = Win;
    }
    __bf16* bh = Bhi + (size_t)l * DH * DH;
    __bf16* bl = Blo + (size_t)l * DH * DH;
    for (int i = threadIdx.x; i < DH * DH; i += 256) {
        int k = i >> 7, j = i & 127;
        float v = beta * W[i] + ((k == j) ? ob : 0.f);
        __bf16 hv = (__bf16)v;
        int t = j >> 4, n = j & 15, ks = k >> 5, quad = (k >> 3) & 3, e = k & 7;
        int off = ((t * 4 + ks) * 64 + quad * 16 + n) * 8 + e;
        bh[off] = hv;
        bl[off] = (__bf16)(v - (float)hv);
    }
}

__global__ void k_prep_out(const float* __restrict__ Wout, __bf16* __restrict__ Bhi, __bf16* __restrict__ Blo) {
    for (int i = threadIdx.x; i < DH * 48; i += 256) {
        int k = i / 48, j = i % 48;
        float v = (j < 40) ? Wout[k * 40 + j] : 0.f;
        __bf16 hv = (__bf16)v;
        int t = j >> 4, n = j & 15, ks = k >> 5, quad = (k >> 3) & 3, e = k & 7;
        int off = ((t * 4 + ks) * 64 + quad * 16 + n) * 8 + e;
        Bhi[off] = hv;
        Blo[off] = (__bf16)(v - (float)hv);
    }
}

__device__ inline void split8(const float* p, bf16x8& hi, bf16x8& lo) {
    f32x4 v0 = *(const f32x4*)p;
    f32x4 v1 = *(const f32x4*)(p + 4);
#pragma unroll
    for (int j = 0; j < 4; ++j) {
        __bf16 h0 = (__bf16)v0[j];
        hi[j] = h0;
        lo[j] = (__bf16)(v0[j] - (float)h0);
        __bf16 h1 = (__bf16)v1[j];
        hi[4 + j] = h1;
        lo[4 + j] = (__bf16)(v1[j] - (float)h1);
    }
}

#define MFMA(a, b, c) __builtin_amdgcn_mfma_f32_16x16x32_bf16(a, b, c, 0, 0, 0)

// ---------------- int8 group quantization (32-feature groups, pow2 scale) ----------------
__device__ inline float dec_scale(unsigned int sc4, int ks) {
    return __uint_as_float(((sc4 >> (8 * ks)) & 0xffu) << 23);
}

#define DEC_DW(dw, wsv, a0, a1, a2, a3)                         \
    {                                                           \
        a0 = fmaf(wsv, (float)((dw)&0xffu), a0);                \
        a1 = fmaf(wsv, (float)(((dw) >> 8) & 0xffu), a1);       \
        a2 = fmaf(wsv, (float)(((dw) >> 16) & 0xffu), a2);      \
        a3 = fmaf(wsv, (float)((dw) >> 24), a3);                \
    }

#define EDGE_FMA(S4, W, RA, RB)                                       \
    {                                                                 \
        float _w = (W);                                               \
        float _w0 = _w * dec_scale(S4, 0);                            \
        float _w1 = _w * dec_scale(S4, 1);                            \
        float _w2 = _w * dec_scale(S4, 2);                            \
        float _w3 = _w * dec_scale(S4, 3);                            \
        sw0 += _w0; sw1 += _w1; sw2 += _w2; sw3 += _w3;               \
        DEC_DW((RA).x, _w0, acc[0][0], acc[0][1], acc[0][2], acc[0][3]); \
        DEC_DW((RA).y, _w0, acc[0][4], acc[0][5], acc[0][6], acc[0][7]); \
        DEC_DW((RA).z, _w1, acc[1][0], acc[1][1], acc[1][2], acc[1][3]); \
        DEC_DW((RA).w, _w1, acc[1][4], acc[1][5], acc[1][6], acc[1][7]); \
        DEC_DW((RB).x, _w2, acc[2][0], acc[2][1], acc[2][2], acc[2][3]); \
        DEC_DW((RB).y, _w2, acc[2][4], acc[2][5], acc[2][6], acc[2][7]); \
        DEC_DW((RB).z, _w3, acc[3][0], acc[3][1], acc[3][2], acc[3][3]); \
        DEC_DW((RB).w, _w3, acc[3][4], acc[3][5], acc[3][6], acc[3][7]); \
    }

// x0 bf16 -> int8 groups (one thread per 32-feature group), fragment-contiguous layout
__global__ void k_cvt8(const __bf16* __restrict__ src, unsigned char* __restrict__ q8,
                       unsigned char* __restrict__ sc) {
    int t = blockIdx.x * 256 + threadIdx.x;
    if (t >= NN * 4) return;
    int node = t >> 2, ks = t & 3;
    const __bf16* p = src + (size_t)node * DH + ks * 32;
    float v[32];
    float mx = 0.f;
#pragma unroll
    for (int i = 0; i < 4; ++i) {
        bf16x8 b = *(const bf16x8*)(p + i * 8);
#pragma unroll
        for (int c = 0; c < 8; ++c) {
            float f = (float)b[c];
            v[i * 8 + c] = f;
            mx = fmaxf(mx, fabsf(f));
        }
    }
    unsigned int em = (__float_as_uint(mx) >> 23) & 0xffu;
    unsigned int eb;
    float sinv;
    if (em < 7) { eb = 0; sinv = 0.f; }
    else { eb = em - 6; sinv = __uint_as_float((254 - eb) << 23); }
    sc[(size_t)node * 4 + ks] = (unsigned char)eb;
    unsigned char* bp = q8 + (size_t)node * 128 + (ks >> 1) * 64 + (ks & 1) * 8;
#pragma unroll
    for (int q = 0; q < 4; ++q) {
        uint2 w;
        w.x = 0; w.y = 0;
#pragma unroll
        for (int c = 0; c < 4; ++c) {
            unsigned int q0 = (unsigned int)rintf(fminf(fmaf(v[q * 8 + c], sinv, 128.f), 255.f));
            unsigned int q1 = (unsigned int)rintf(fminf(fmaf(v[q * 8 + 4 + c], sinv, 128.f), 255.f));
            w.x |= q0 << (8 * c);
            w.y |= q1 << (8 * c);
        }
        *(uint2*)(bp + q * 16) = w;
    }
}

// ---------------- FUSED SpMM + mix + layer GEMM (int8, pipelined; permuted space) ----------------
// Data is RELABELED into degree-sorted order, so this kernel has zero perm
// lookups: sequential ep windows per lane-group, sequential aout writes, and
// near-uniform trip counts within each 16-node group (R8's divergence win with
// R7's access pattern).
__global__ __launch_bounds__(512, 4) void k_spmm_gemm(const unsigned char* __restrict__ hin8,
                                                      const unsigned char* __restrict__ hinsc,
                                                      const unsigned char* __restrict__ x08,
                                                      const unsigned char* __restrict__ x0sc,
                                                      const int* __restrict__ rp, const int2* __restrict__ ep,
                                                      __bf16* __restrict__ aout,
                                                      const __bf16* __restrict__ Bhi, const __bf16* __restrict__ Blo,
                                                      float* __restrict__ stats32) {
    __shared__ __bf16 Bs[2 * DH * DH];  // [hi|lo] in MFMA fragment order
    __shared__ float red[2][8][DH];
    int tid = threadIdx.x;
    {
        const f32x4* sh = (const f32x4*)Bhi;
        const f32x4* sl = (const f32x4*)Blo;
        f32x4* dh = (f32x4*)Bs;
        f32x4* dl = (f32x4*)(Bs + DH * DH);
#pragma unroll
        for (int i = 0; i < 4; ++i) {
            dh[tid + i * 512] = sh[tid + i * 512];
            dl[tid + i * 512] = sl[tid + i * 512];
        }
    }
    // no sync yet: gather phase doesn't touch Bs; sync sits right before MFMA.

    int wave = tid >> 6, lane = tid & 63;
    int n = lane & 15, quad = lane >> 4;
    int r0 = blockIdx.x * 128 + wave * 16;
    int node = r0 + n;
    int nc = (node < NN) ? node : (NN - 1);

    float acc[4][8];
#pragma unroll
    for (int ks = 0; ks < 4; ++ks)
#pragma unroll
        for (int c = 0; c < 8; ++c) acc[ks][c] = 0.f;
    float sw0 = 0.f, sw1 = 0.f, sw2 = 0.f, sw3 = 0.f;

    // x0 self-term loads
    unsigned xs4 = *(const unsigned*)&x0sc[(size_t)nc * 4];
    const unsigned char* xb = x08 + (size_t)nc * 128 + quad * 16;
    uint4 xa = *(const uint4*)xb;
    uint4 xc = *(const uint4*)(xb + 64);

    int s = 0, e = 0;
    if (node < NN) { s = rp[node]; e = rp[node + 1]; }
    int cnt = e - s;
    int npairs = cnt >> 1;

    const unsigned char* hb = hin8 + quad * 16;

    int2 cP0, cP1, fP0, fP1;
    unsigned cS0, cS1;
    uint4 cA0, cB0, cA1, cB1;
    if (npairs > 0) {
        cP0 = ep[s]; cP1 = ep[s + 1];
        cS0 = *(const unsigned*)&hinsc[(size_t)cP0.x * 4];
        cS1 = *(const unsigned*)&hinsc[(size_t)cP1.x * 4];
        const unsigned char* b0 = hb + (size_t)cP0.x * 128;
        const unsigned char* b1 = hb + (size_t)cP1.x * 128;
        cA0 = *(const uint4*)b0; cB0 = *(const uint4*)(b0 + 64);
        cA1 = *(const uint4*)b1; cB1 = *(const uint4*)(b1 + 64);
        int jf = s + 2; if (jf > EE - 2) jf = EE - 2;
        fP0 = ep[jf]; fP1 = ep[jf + 1];
    }

    EDGE_FMA(xs4, 0.1f, xa, xc);   // weight 0.1 on x0 (alpha mix)

    int j = s;
    for (int it = 0; it < npairs; ++it) {
        // stage 1: ep prefetch for pair it+2 (clamped speculative)
        int j2 = j + 4; if (j2 > EE - 2) j2 = EE - 2;
        int2 eN0 = ep[j2], eN1 = ep[j2 + 1];
        // stage 2: scales + rows for pair it+1
        unsigned tS0 = *(const unsigned*)&hinsc[(size_t)fP0.x * 4];
        unsigned tS1 = *(const unsigned*)&hinsc[(size_t)fP1.x * 4];
        const unsigned char* b0 = hb + (size_t)fP0.x * 128;
        const unsigned char* b1 = hb + (size_t)fP1.x * 128;
        uint4 tA0 = *(const uint4*)b0, tB0 = *(const uint4*)(b0 + 64);
        uint4 tA1 = *(const uint4*)b1, tB1 = *(const uint4*)(b1 + 64);
        // stage 3: fma pair it
        EDGE_FMA(cS0, __int_as_float(cP0.y), cA0, cB0);
        EDGE_FMA(cS1, __int_as_float(cP1.y), cA1, cB1);
        cP0 = fP0; cP1 = fP1; fP0 = eN0; fP1 = eN1;
        cS0 = tS0; cS1 = tS1;
        cA0 = tA0; cB0 = tB0; cA1 = tA1; cB1 = tB1;
        j += 2;
    }
    if (cnt & 1) {
        int2 pe = ep[e - 1];
        unsigned s4 = *(const unsigned*)&hinsc[(size_t)pe.x * 4];
        const unsigned char* bp = hb + (size_t)pe.x * 128;
        uint4 ra = *(const uint4*)bp, rb = *(const uint4*)(bp + 64);
        EDGE_FMA(s4, __int_as_float(pe.y), ra, rb);
    }

    // bias correction (u8 -> u8-128) + bf16 A fragments
    bf16x8 av[4];
    {
        float sws[4] = {sw0, sw1, sw2, sw3};
#pragma unroll
        for (int ks = 0; ks < 4; ++ks)
#pragma unroll
            for (int c = 0; c < 8; ++c)
                av[ks][c] = (__bf16)(acc[ks][c] - 128.0f * sws[ks]);
    }

    __syncthreads();  // Bs staging complete across all waves

    f32x4 gacc[8];
#pragma unroll
    for (int t = 0; t < 8; ++t) gacc[t] = (f32x4){0.f, 0.f, 0.f, 0.f};

#pragma unroll
    for (int ks = 0; ks < 4; ++ks) {
#pragma unroll
        for (int t = 0; t < 8; ++t) {
            int base = ((t * 4 + ks) * 64 + lane) * 8;
            bf16x8 bh = *(const bf16x8*)&Bs[base];
            bf16x8 bl = *(const bf16x8*)&Bs[DH * DH + base];
            gacc[t] = MFMA(av[ks], bh, gacc[t]);
            gacc[t] = MFMA(av[ks], bl, gacc[t]);
        }
    }

#pragma unroll
    for (int t = 0; t < 8; ++t) {
        float sm = 0.f, qq = 0.f;
#pragma unroll
        for (int r = 0; r < 4; ++r) {
            int row = r0 + quad * 4 + r;
            float v = gacc[t][r];
            if (row < NN) {
                aout[(size_t)row * DH + t * 16 + n] = (__bf16)v;
                sm += v;
                qq += v * v;
            }
        }
        sm += __shfl_xor(sm, 16); sm += __shfl_xor(sm, 32);
        qq += __shfl_xor(qq, 16); qq += __shfl_xor(qq, 32);
        if (quad == 0) {
            red[0][wave][t * 16 + n] = sm;
            red[1][wave][t * 16 + n] = qq;
        }
    }
    __syncthreads();
    if (tid < 256) {
        int which = tid >> 7, jj = tid & 127;
        float tot = 0.f;
#pragma unroll
        for (int w = 0; w < 8; ++w) tot += red[which][w][jj];
        atomicAdd(&stats32[(size_t)(blockIdx.x & (NSLOT - 1)) * 256 + tid], tot);
    }
}

// ---------------- input GEMM: x0[i] = relu(X[perm[i]] @ Win + bin), 512 threads ----------------
// 8 waves share one 64KB B-tile -> 16 waves/CU (R8 showed this kernel at 16%
// occupancy was the new top dispatch). X rows are 512B -> full-line reads even
// permuted. x0 written sequentially in permuted space.
__global__ __launch_bounds__(512, 4) void k_lin_in(const float* __restrict__ X, const int* __restrict__ perm,
                                                   const __bf16* __restrict__ Bhi, const __bf16* __restrict__ Blo,
                                                   const float* __restrict__ bin, __bf16* __restrict__ x0) {
    __shared__ __bf16 Bs[2 * DH * DH];
    int tid = threadIdx.x;
    {
        const f32x4* sh = (const f32x4*)Bhi;
        const f32x4* sl = (const f32x4*)Blo;
        f32x4* dh = (f32x4*)Bs;
        f32x4* dl = (f32x4*)(Bs + DH * DH);
#pragma unroll
        for (int i = 0; i < 4; ++i) {
            dh[tid + i * 512] = sh[tid + i * 512];
            dl[tid + i * 512] = sl[tid + i * 512];
        }
    }
    __syncthreads();

    int wave = tid >> 6, lane = tid & 63;
    int n = lane & 15, quad = lane >> 4;
    int r0 = blockIdx.x * 128 + wave * 16;
    int arow = r0 + n;
    if (arow > NN - 1) arow = NN - 1;
    const float* pa = X + (size_t)perm[arow] * DH + quad * 8;

    f32x4 acc[8];
#pragma unroll
    for (int t = 0; t < 8; ++t) acc[t] = (f32x4){0.f, 0.f, 0.f, 0.f};

#pragma unroll
    for (int ks = 0; ks < 4; ++ks) {
        bf16x8 ah, al;
        split8(pa + ks * 32, ah, al);
#pragma unroll
        for (int t = 0; t < 8; ++t) {
            int base = ((t * 4 + ks) * 64 + lane) * 8;
            bf16x8 bh = *(const bf16x8*)&Bs[base];
            bf16x8 bl = *(const bf16x8*)&Bs[DH * DH + base];
            acc[t] = MFMA(ah, bh, acc[t]);
            acc[t] = MFMA(al, bh, acc[t]);
            acc[t] = MFMA(ah, bl, acc[t]);
        }
    }

#pragma unroll
    for (int t = 0; t < 8; ++t) {
        float bj = bin[t * 16 + n];
#pragma unroll
        for (int r = 0; r < 4; ++r) {
            int row = r0 + quad * 4 + r;
            if (row < NN) {
                float v = fmaxf(acc[t][r] + bj, 0.f);
                x0[(size_t)row * DH + t * 16 + n] = (__bf16)v;
            }
        }
    }
}

// ---------------- output GEMM: out[perm[i]] = h[i] @ Wout + bout ----------------
__global__ __launch_bounds__(256) void k_gemm_out(const __bf16* __restrict__ A, const int* __restrict__ perm,
                                                  const __bf16* __restrict__ Bhi, const __bf16* __restrict__ Blo,
                                                  const float* __restrict__ bout, float* __restrict__ out) {
    __shared__ __bf16 Bs[2 * 48 * DH];
    int tid = threadIdx.x;
    {
        const f32x4* sh = (const f32x4*)Bhi;
        const f32x4* sl = (const f32x4*)Blo;
        f32x4* dh = (f32x4*)Bs;
        f32x4* dl = (f32x4*)(Bs + 48 * DH);
#pragma unroll
        for (int i = 0; i < 3; ++i) {
            dh[tid + i * 256] = sh[tid + i * 256];
            dl[tid + i * 256] = sl[tid + i * 256];
        }
    }
    __syncthreads();

    int wave = tid >> 6, lane = tid & 63;
    int n = lane & 15, quad = lane >> 4;
    int r0 = blockIdx.x * 64 + wave * 16;
    int arow = r0 + n;
    if (arow > NN - 1) arow = NN - 1;
    const __bf16* pa = A + (size_t)arow * DH + quad * 8;

    f32x4 acc[3];
#pragma unroll
    for (int t = 0; t < 3; ++t) acc[t] = (f32x4){0.f, 0.f, 0.f, 0.f};

#pragma unroll
    for (int ks = 0; ks < 4; ++ks) {
        bf16x8 av = *(const bf16x8*)(pa + ks * 32);
#pragma unroll
        for (int t = 0; t < 3; ++t) {
            int base = ((t * 4 + ks) * 64 + lane) * 8;
            bf16x8 bh = *(const bf16x8*)&Bs[base];
            bf16x8 bl = *(const bf16x8*)&Bs[48 * DH + base];
            acc[t] = MFMA(av, bh, acc[t]);
            acc[t] = MFMA(av, bl, acc[t]);
        }
    }

    int prow[4];
#pragma unroll
    for (int r = 0; r < 4; ++r) {
        int row = r0 + quad * 4 + r;
        prow[r] = (row < NN) ? perm[row] : 0;
    }

#pragma unroll
    for (int t = 0; t < 3; ++t) {
        int j = t * 16 + n;
        float bj = (j < 40) ? bout[j] : 0.f;
#pragma unroll
        for (int r = 0; r < 4; ++r) {
            int row = r0 + quad * 4 + r;
            if (row < NN && j < 40) out[(size_t)prow[r] * 40 + j] = acc[t][r] + bj;
        }
    }
}

// ---------------- fused slot-reduce + BN-finalize + update + int8 re-encode (permuted space) ----------------
__global__ __launch_bounds__(256) void k_update(const __bf16* __restrict__ a, const __bf16* __restrict__ hin,
                                                __bf16* __restrict__ hout,
                                                unsigned char* __restrict__ h8, unsigned char* __restrict__ hsc,
                                                const float* __restrict__ stats32,
                                                const float* __restrict__ gamma, const float* __restrict__ bbeta) {
    __shared__ float scb[DH], shb[DH];
    int tid = threadIdx.x;
    if (tid < DH) {
        float s = 0.f, q = 0.f;
#pragma unroll
        for (int sl = 0; sl < NSLOT; ++sl) {
            s += stats32[(size_t)sl * 256 + tid];
            q += stats32[(size_t)sl * 256 + 128 + tid];
        }
        float mu = s * (1.0f / NN);
        float var = q * (1.0f / NN) - mu * mu;
        if (var < 0.f) var = 0.f;
        float sc = gamma[tid] * rsqrtf(var + 1e-5f);
        scb[tid] = sc;
        shb[tid] = bbeta[tid] - mu * sc;
    }
    __syncthreads();

    int idx = blockIdx.x * 256 + tid;
    int sub = idx & 15;
    int j0 = sub * 8;
    bf16x8 av = ((const bf16x8*)a)[idx];
    bf16x8 hv = ((const bf16x8*)hin)[idx];
    bf16x8 o;
    float vv[8];
    float mx = 0.f;
#pragma unroll
    for (int c = 0; c < 8; ++c) {
        int j = j0 + c;
        float v = fmaxf(fmaf((float)av[c], scb[j], shb[j]) + (float)hv[c], 0.f);
        vv[c] = v;
        mx = fmaxf(mx, v);          // relu'd: v >= 0
        o[c] = (__bf16)v;
    }
    ((bf16x8*)hout)[idx] = o;

    // group max across the 4 threads sharing cols [ks*32, ks*32+32)
    mx = fmaxf(mx, __shfl_xor(mx, 1));
    mx = fmaxf(mx, __shfl_xor(mx, 2));
    unsigned int em = (__float_as_uint(mx) >> 23) & 0xffu;
    unsigned int eb;
    float sinv;
    if (em < 7) { eb = 0; sinv = 0.f; }
    else { eb = em - 6; sinv = __uint_as_float((254 - eb) << 23); }
    if ((tid & 3) == 0) hsc[(size_t)(idx >> 4) * 4 + (sub >> 2)] = (unsigned char)eb;
    uint2 pk;
    pk.x = 0; pk.y = 0;
#pragma unroll
    for (int c = 0; c < 4; ++c) {
        unsigned int q0 = (unsigned int)rintf(fminf(fmaf(vv[c], sinv, 128.f), 255.f));
        unsigned int q1 = (unsigned int)rintf(fminf(fmaf(vv[4 + c], sinv, 128.f), 255.f));
        pk.x |= q0 << (8 * c);
        pk.y |= q1 << (8 * c);
    }
    // fragment-contiguous position: P = (ks>>1)*64 + q*16 + (ks&1)*8, ks=sub>>2, q=sub&3
    unsigned wpos = ((sub >> 3) & 1) * 64 + (sub & 3) * 16 + ((sub >> 2) & 1) * 8;
    *(uint2*)&h8[(size_t)(idx >> 4) * 128 + wpos] = pk;
}

extern "C" void kernel_launch(void* const* d_in, const int* in_sizes, int n_in,
                              void* d_out, int out_size, void* d_ws, size_t ws_size,
                              hipStream_t stream) {
    const float* x = (const float*)d_in[0];
    const float* ew = (const float*)d_in[1];
    const float* Win = (const float*)d_in[2];
    const float* bin = (const float*)d_in[3];
    const float* convW = (const float*)d_in[4];
    const float* gamma = (const float*)d_in[5];
    const float* bbeta = (const float*)d_in[6];
    const float* Wout = (const float*)d_in[7];
    const float* bout = (const float*)d_in[8];
    const int* erow = (const int*)d_in[9];
    const int* ecol = (const int*)d_in[10];
    float* out = (float*)d_out;

    char* wsp = (char*)d_ws;
    size_t off = 0;
    auto alloc = [&](size_t bytes) -> void* {
        void* p = wsp + off;
        off += (bytes + 255) & ~(size_t)255;
        return p;
    };
    __bf16* x0 = (__bf16*)alloc((size_t)NN * DH * 2);
    __bf16* h = (__bf16*)alloc((size_t)NN * DH * 2);
    __bf16* a = (__bf16*)alloc((size_t)NN * DH * 2);
    unsigned char* x08 = (unsigned char*)alloc((size_t)NN * DH);
    unsigned char* h8 = (unsigned char*)alloc((size_t)NN * DH);
    unsigned char* x0sc = (unsigned char*)alloc((size_t)NN * 4);
    unsigned char* hsc = (unsigned char*)alloc((size_t)NN * 4);
    int* rp = (int*)alloc((NN + 1) * 4);
    int* perm = (int*)alloc((size_t)NN * 4);
    int* iperm = (int*)alloc((size_t)NN * 4);
    int* cnt2 = (int*)alloc((size_t)NN * 4);
    int* dpre = (int*)alloc(64 * 4);
    // zero-init region: cnt | fil | stats32 | dbin | dfil as ONE memset
    size_t zero_bytes = (size_t)NN * 4 + (size_t)NN * 4 + (size_t)NL * NSLOT * 256 * 4 + 128 * 4;
    int* cnt = (int*)alloc(zero_bytes);
    int* fil = cnt + NN;
    float* stats32 = (float*)(fil + NN);
    int* dbin = (int*)(stats32 + (size_t)NL * NSLOT * 256);
    int* dfil = dbin + 64;
    int2* ep = (int2*)alloc((size_t)EE * 8);
    int* part = (int*)alloc(256 * 4);
    __bf16* Bhi = (__bf16*)alloc((size_t)(NL + 1) * DH * DH * 2);
    __bf16* Blo = (__bf16*)alloc((size_t)(NL + 1) * DH * DH * 2);
    __bf16* Bohi = (__bf16*)alloc((size_t)DH * 48 * 2);
    __bf16* Bolo = (__bf16*)alloc((size_t)DH * 48 * 2);

    hipMemsetAsync(cnt, 0, zero_bytes, stream);

    k_hist<<<3125, 256, 0, stream>>>(erow, cnt);
    k_dhist<<<391, 256, 0, stream>>>(cnt, dbin);
    k_pscan<<<1, 64, 0, stream>>>(dbin, dpre);
    k_pscatter<<<391, 256, 0, stream>>>(cnt, dpre, dfil, perm);
    k_iperm<<<391, 256, 0, stream>>>(perm, cnt, iperm, cnt2);
    k_scan1<<<196, 512, 0, stream>>>(cnt2, rp, part);
    k_scan2<<<1, 256, 0, stream>>>(part, 196);
    k_scan3<<<196, 512, 0, stream>>>(rp, part);
    k_fill<<<25000, 256, 0, stream>>>(erow, ecol, ew, rp, iperm, fil, ep);

    k_prep_w<<<NL + 1, 256, 0, stream>>>(convW, Win, Bhi, Blo);
    k_prep_out<<<1, 256, 0, stream>>>(Wout, Bohi, Bolo);

    k_lin_in<<<SG_GRID, 512, 0, stream>>>(x, perm, Bhi + (size_t)NL * DH * DH, Blo + (size_t)NL * DH * DH, bin, x0);
    k_cvt8<<<1563, 256, 0, stream>>>(x0, x08, x0sc);

    for (int l = 0; l < NL; ++l) {
        const unsigned char* hin8 = (l == 0) ? x08 : h8;
        const unsigned char* hinsc = (l == 0) ? x0sc : hsc;
        const __bf16* hin = (l == 0) ? x0 : h;
        float* st = stats32 + (size_t)l * NSLOT * 256;
        k_spmm_gemm<<<SG_GRID, 512, 0, stream>>>(hin8, hinsc, x08, x0sc, rp, ep, a,
                                                 Bhi + (size_t)l * DH * DH, Blo + (size_t)l * DH * DH, st);
        k_update<<<6250, 256, 0, stream>>>(a, hin, h, h8, hsc, st, gamma + l * DH, bbeta + l * DH);
    }
    k_gemm_out<<<GEMM_GRID, 256, 0, stream>>>(h, perm, Bohi, Bolo, bout, out);
}